// Round 13
// baseline (499.282 us; speedup 1.0000x reference)
//
#include <hip/hip_runtime.h>

// Problem constants (fixed by the reference)
constexpr int Bc = 32, Sc = 1024, Hc = 256, Pc = 96, Lc = 200, Oc = 200, Ec = 64;
constexpr int Mtot = Bc * Sc;
constexpr float DT = 0.25f;     // 1/N_EULER
constexpr int KP = 224;         // padded L/O dim (7*32)

enum { MODE_ENC = 0, MODE_QKV = 3, MODE_OUT = 4, MODE_BF16OUT = 5 };

typedef short bf16x8 __attribute__((ext_vector_type(8)));
typedef float f32x4 __attribute__((ext_vector_type(4)));
typedef unsigned short u16x8 __attribute__((ext_vector_type(8)));
typedef unsigned int u32x2 __attribute__((ext_vector_type(2)));

__device__ inline unsigned short f2bf(float x) {
    union { float f; unsigned int u; } v; v.f = x;
    unsigned int r = v.u + 0x7FFFu + ((v.u >> 16) & 1u);   // RNE
    return (unsigned short)(r >> 16);
}
__device__ inline float bf2f(unsigned short x) {
    union { unsigned int u; float f; } v; v.u = ((unsigned int)x) << 16;
    return v.f;
}
// rcp-form tanh: 1 - 2/(e^{2x}+1). 6 ops, no clamp needed:
// x->+inf: e=inf, rcp=0, y=1; x->-inf: e=0, rcp(1)=1, y=-1.
__device__ inline float fast_tanh(float x) {
    float e = __expf(2.f * x);
    float r = __frcp_rn(e + 1.f);
    return fmaf(-2.f, r, 1.f);
}
// pack two f32 -> two bf16 (RNE) in one instruction; lo=bf16(a), hi=bf16(b)
__device__ inline unsigned int cvt_pk_bf16(float a, float b) {
    unsigned int r;
    asm("v_cvt_pk_bf16_f32 %0, %1, %2" : "=v"(r) : "v"(a), "v"(b));
    return r;
}

// ---------------------------------------------------------------------------
__global__ __launch_bounds__(256) void eco_kernel(
    const float* __restrict__ eco_data, const float* __restrict__ W_eco,
    const float* __restrict__ b_eco, float* __restrict__ eco_vec)
{
    const int b = blockIdx.x, h = threadIdx.x;
    float acc = b_eco[h];
    #pragma unroll
    for (int e = 0; e < Ec; e++)
        acc = fmaf(eco_data[b * Ec + e], W_eco[(size_t)e * Hc + h], acc);
    eco_vec[(size_t)b * Hc + h] = acc;
}

// ---------------------------------------------------------------------------
// All five weight transposes in ONE dispatch (13 z-slices):
//   z 0-2 : W_in  [256][200] -> WinT  + z*256*256   (Kpad 256, Npad 256)
//   z 3-5 : W_f1  [200][200] -> Wf1T  + i*224*256   (Kpad 224, Npad 256)
//   z 6-8 : W_f2  [200][200] -> Wf2T  + i*224*256
//   z 9-11: W_out [200][256] -> WoutT + i*224*256
//   z 12  : W_lin [256][ 96] -> WlinT               (Kpad 256, Npad 128)
// ---------------------------------------------------------------------------
__global__ void wtrans_all(
    const float* __restrict__ W_in, const float* __restrict__ W_f1,
    const float* __restrict__ W_f2, const float* __restrict__ W_out,
    const float* __restrict__ W_lin,
    unsigned short* __restrict__ WinT, unsigned short* __restrict__ Wf1T,
    unsigned short* __restrict__ Wf2T, unsigned short* __restrict__ WoutT,
    unsigned short* __restrict__ WlinT)
{
    const int z = blockIdx.z;
    const int n = blockIdx.x * 16 + threadIdx.x;
    const int k = blockIdx.y * 16 + threadIdx.y;

    const float* W; unsigned short* WT;
    int K, N, Kpad, Npad;
    if (z < 3)       { W = W_in  + (size_t)z * 256 * 200;       WT = WinT  + (size_t)z * 256 * 256;       K = 256; N = 200; Kpad = 256; Npad = 256; }
    else if (z < 6)  { W = W_f1  + (size_t)(z - 3) * 200 * 200; WT = Wf1T  + (size_t)(z - 3) * 224 * 256; K = 200; N = 200; Kpad = 224; Npad = 256; }
    else if (z < 9)  { W = W_f2  + (size_t)(z - 6) * 200 * 200; WT = Wf2T  + (size_t)(z - 6) * 224 * 256; K = 200; N = 200; Kpad = 224; Npad = 256; }
    else if (z < 12) { W = W_out + (size_t)(z - 9) * 200 * 256; WT = WoutT + (size_t)(z - 9) * 224 * 256; K = 200; N = 256; Kpad = 224; Npad = 256; }
    else             { W = W_lin;                               WT = WlinT;                               K = 256; N =  96; Kpad = 256; Npad = 128; }

    if (n >= Npad || k >= Kpad) return;
    float v = (n < N && k < K) ? W[(size_t)k * N + n] : 0.f;
    WT[(size_t)n * Kpad + k] = f2bf(v);
}

// ---------------------------------------------------------------------------
// bf16 MFMA GEMM, 128x128 tile, 4 waves of 64x64, 16x16x32 MFMA.
// r24 (green, -23 us): LDS DOUBLE-BUFFER — 2x As/Bs (40,960 B), ONE barrier
// per k-step, next-tile global loads issued before this tile's MFMAs, stores
// into the idle buffer after. Race-free by construction: every conflicting
// access pair on a buffer is separated by the per-iteration barrier.
// MODE_QKV z==2 writes V^T via an LDS bounce (r14: -27 us).
// ---------------------------------------------------------------------------
template <int MODE, typename TA>
__global__ __launch_bounds__(256) void mfma_gemm(
    const TA* __restrict__ A, const unsigned short* __restrict__ WT,
    const float* __restrict__ bias, void* __restrict__ Cv,
    int M, int N, int K, int Kpad,
    size_t aStrideZ, size_t wStrideZ, size_t bStrideZ, size_t cStrideZ,
    const float* __restrict__ timev, const float* __restrict__ wtv,
    const float* __restrict__ eco, const float* __restrict__ trandat,
    unsigned short* __restrict__ Ck, unsigned short* __restrict__ Cvt)
{
    constexpr int LDS_S = 40;
    constexpr int HALF = 128 * LDS_S;            // 5120 u16 per array
    __shared__ unsigned short SM[4 * HALF];      // As0|Bs0|As1|Bs1  40,960 B

    const int tid = threadIdx.x;
    const int z = blockIdx.z;
    const int m0 = blockIdx.y * 128;
    const int n0 = blockIdx.x * 128;

    A    += (size_t)z * aStrideZ;
    WT   += (size_t)z * wStrideZ;
    bias += (size_t)z * bStrideZ;
    float* Cf = (float*)Cv + (size_t)z * cStrideZ;
    unsigned short* Cu = (unsigned short*)Cv + (size_t)z * cStrideZ;
    const float* wtp = wtv ? (wtv + (size_t)z * Lc) : nullptr;

    const int lane = tid & 63, wave = tid >> 6;
    const int wm = (wave & 1) * 64, wn = (wave >> 1) * 64;
    const int fm = lane & 15, fq = lane >> 4;

    f32x4 acc[4][4];
    #pragma unroll
    for (int i = 0; i < 4; i++)
        #pragma unroll
        for (int j = 0; j < 4; j++)
            acc[i][j] = (f32x4){0.f, 0.f, 0.f, 0.f};

    // staging registers
    float4  paf[4];
    ushort4 pau[4];
    u16x8   pb[2];

    auto LOAD = [&](int k0) {
        #pragma unroll
        for (int i = 0; i < 4; i++) {
            const int f = i * 256 + tid;
            const int row = f >> 3, kq = f & 7;
            if constexpr (sizeof(TA) == 4)
                paf[i] = *(const float4*)((const float*)A + (size_t)(m0 + row) * K + k0 + kq * 4);
            else
                pau[i] = *(const ushort4*)((const unsigned short*)A + (size_t)(m0 + row) * K + k0 + kq * 4);
        }
        #pragma unroll
        for (int i = 0; i < 2; i++) {
            const int f = i * 256 + tid;
            const int row = f >> 2, q = f & 3;
            pb[i] = *(const u16x8*)(WT + (size_t)(n0 + row) * Kpad + k0 + q * 8);
        }
    };
    auto STORE = [&](int buf) {
        unsigned short* Asd = SM + buf * 2 * HALF;
        unsigned short* Bsd = Asd + HALF;
        #pragma unroll
        for (int i = 0; i < 4; i++) {
            const int f = i * 256 + tid;
            const int row = f >> 3, kq = f & 7;
            ushort4 s;
            if constexpr (sizeof(TA) == 4) {
                s.x = f2bf(paf[i].x); s.y = f2bf(paf[i].y);
                s.z = f2bf(paf[i].z); s.w = f2bf(paf[i].w);
            } else {
                s = pau[i];
            }
            *(ushort4*)&Asd[row * LDS_S + kq * 4] = s;
        }
        #pragma unroll
        for (int i = 0; i < 2; i++) {
            const int f = i * 256 + tid;
            const int row = f >> 2, q = f & 3;
            *(u16x8*)&Bsd[row * LDS_S + q * 8] = pb[i];
        }
    };

    const int nk = K >> 5;
    // prologue: tile 0 -> buf0
    LOAD(0);
    STORE(0);

    for (int ki = 0; ki < nk; ki++) {
        __syncthreads();        // buf[ki&1] writes visible; buf[(ki+1)&1] reads done
        const unsigned short* Asr = SM + (ki & 1) * 2 * HALF;
        const unsigned short* Bsr = Asr + HALF;

        // issue next-tile global loads (latency hides under ds_reads + MFMAs)
        if (ki + 1 < nk) LOAD((ki + 1) * 32);

        bf16x8 af[4], bfr[4];
        #pragma unroll
        for (int mi = 0; mi < 4; mi++)
            af[mi] = *(const bf16x8*)&Asr[(wm + mi * 16 + fm) * LDS_S + fq * 8];
        #pragma unroll
        for (int nj = 0; nj < 4; nj++)
            bfr[nj] = *(const bf16x8*)&Bsr[(wn + nj * 16 + fm) * LDS_S + fq * 8];
        #pragma unroll
        for (int mi = 0; mi < 4; mi++)
            #pragma unroll
            for (int nj = 0; nj < 4; nj++)
                acc[mi][nj] = __builtin_amdgcn_mfma_f32_16x16x32_bf16(
                    af[mi], bfr[nj], acc[mi][nj], 0, 0, 0);

        // store next tile into the idle buffer
        if (ki + 1 < nk) STORE((ki + 1) & 1);
    }

    // ---- V^T epilogue (MODE_QKV, z==2): LDS bounce, coalesced writes ----
    if (MODE == MODE_QKV && z == 2) {
        constexpr int BSTR = 136;   // bounce row stride (u16); 64x136 fits in SM
        const int bq = m0 >> 10, sq0 = m0 & (Sc - 1);
        const int myhalf = wn >> 6;             // wave's n-half (0 or 1)
        #pragma unroll
        for (int half = 0; half < 2; half++) {
            __syncthreads();                    // SM free
            if (myhalf == half) {
                #pragma unroll
                for (int mi = 0; mi < 4; mi++)
                    #pragma unroll
                    for (int nj = 0; nj < 4; nj++) {
                        const int nn = n0 + wn + nj * 16 + fm;
                        const float bv = bias[nn];
                        const float ev = eco[(size_t)bq * Hc + nn];
                        #pragma unroll
                        for (int r = 0; r < 4; r++) {
                            const int mm = m0 + wm + mi * 16 + fq * 4 + r;
                            float v = acc[mi][nj][r] + bv + ev;
                            if (trandat[(size_t)mm * Hc + (Hc - 1)] == 0.f) v = 0.f;
                            SM[(nj * 16 + fm) * BSTR + wm + mi * 16 + fq * 4 + r] = f2bf(v);
                        }
                    }
            }
            __syncthreads();                    // bounce half ready
            #pragma unroll
            for (int i = 0; i < 4; i++) {
                const int vv = i * 256 + tid;   // 1024 = 64 rows x 16 vecs
                const int nl = vv >> 4, vc = vv & 15;
                *(u16x8*)&Cvt[((size_t)bq * Hc + n0 + half * 64 + nl) * Sc + sq0 + vc * 8] =
                    *(const u16x8*)&SM[nl * BSTR + vc * 8];
            }
        }
        return;
    }

    // ---- standard epilogue: C/D layout col = lane&15, row = quad*4 + reg ----
    #pragma unroll
    for (int mi = 0; mi < 4; mi++) {
        #pragma unroll
        for (int nj = 0; nj < 4; nj++) {
            const int nn = n0 + wn + nj * 16 + fm;
            if (nn >= N) continue;
            const float bv = (MODE == MODE_BF16OUT) ? 0.f
                           : ((MODE == MODE_ENC && nn >= Lc) ? 0.f : bias[nn]);
            #pragma unroll
            for (int r = 0; r < 4; r++) {
                const int mm = m0 + wm + mi * 16 + fq * 4 + r;
                float v = acc[mi][nj][r] + bv;
                if (MODE == MODE_ENC) {
                    float vv = (nn < Lc) ? fast_tanh(v + timev[mm] * wtp[nn]) : 0.f;
                    Cu[(size_t)mm * N + nn] = f2bf(vv);
                } else if (MODE == MODE_QKV) {
                    v += eco[(size_t)(mm >> 10) * Hc + nn];
                    if (trandat[(size_t)mm * Hc + (Hc - 1)] == 0.f) v = 0.f;
                    if (z == 0)      ((unsigned short*)Cv)[(size_t)mm * Hc + nn] = f2bf(v * 0.0625f);
                    else             Ck[(size_t)mm * Hc + nn] = f2bf(v);
                } else if (MODE == MODE_BF16OUT) {
                    Cu[(size_t)mm * N + nn] = f2bf(v);
                } else {
                    Cf[(size_t)mm * N + nn] = v;
                }
            }
        }
    }
}

// ---------------------------------------------------------------------------
// Fused 4-iteration Euler solve — r20 state VERBATIM (173.7-175.5 us
// measured green three times): r5/r16 structure + swapped-operand MFMA + b64
// vector scatter/RMW + cvt_pk + bias LDS, HS=232/WS=40. CLOSED AVENUES:
// 64-row/2-blocks-CU (r11: occupancy stayed 22.9%, MFMA density halved ->
// 229 us); stride destripe (r8: breaks b128 alignment -> 500 us).
// Dynamic LDS 117,504 B.
// ---------------------------------------------------------------------------
__global__ __launch_bounds__(512, 2) void euler_fused(
    unsigned short* __restrict__ hg,       // [3][M][224] bf16, in/out
    const unsigned short* __restrict__ W1, // [3][256][224] bf16
    const unsigned short* __restrict__ W2, // [3][256][224] bf16
    const float* __restrict__ b1g, const float* __restrict__ b2g)
{
    constexpr int HS = 232;   // h LDS stride (u16)
    constexpr int WS = 40;    // W / hid chunk stride (u16)
    extern __shared__ unsigned short lds[];
    unsigned short* hs  = lds;                 // [128][232]  59,392 B
    unsigned short* wsb[2] = { lds + 29696, lds + 38656 };   // [224][40] each
    unsigned short* hcb[2] = { lds + 47616, lds + 52736 };   // [128][40] each
    float* bs = (float*)(lds + 57856);         // b1[224] | b2[224]  1,792 B

    const int tid = threadIdx.x;
    const int z = blockIdx.y;
    const int m0 = blockIdx.x * 128;
    unsigned short* hrow = hg + ((size_t)z * Mtot + m0) * KP;
    const unsigned short* W1z = W1 + (size_t)z * 256 * KP;
    const unsigned short* W2z = W2 + (size_t)z * 256 * KP;

    const int lane = tid & 63, w = tid >> 6;
    const int wm = (w & 3) * 32, wn = (w >> 2) * 112;
    const int fm = lane & 15, fq = lane >> 4;

    const int sr = tid >> 2, sq = tid & 3;
    const bool s2 = (tid < 384);

    // stage biases into LDS (zero-padded to 224 each)
    if (tid < 448) {
        float v;
        if (tid < 224) v = (tid < Oc) ? b1g[z * Oc + tid] : 0.f;
        else { const int t = tid - 224; v = (t < Lc) ? b2g[z * Lc + t] : 0.f; }
        bs[tid] = v;
    }

    // prefetch W1 chunk 0
    u16x8 pr0, pr1;
    pr0 = *(const u16x8*)&W1z[sr * KP + sq * 8];
    if (s2) pr1 = *(const u16x8*)&W1z[(sr + 128) * KP + sq * 8];

    // stage h tile: 128 x 224
    #pragma unroll
    for (int i = 0; i < 7; i++) {
        const int f = i * 512 + tid;
        const int r = f / 28, c = (f % 28) * 8;
        *(u16x8*)&hs[r * HS + c] = *(const u16x8*)&hrow[(size_t)r * KP + c];
    }

    for (int it = 0; it < 4; it++) {
        // ================= phase 1: hid = tanh(h @ W1 + b1) =================
        __syncthreads();                       // B0: hs/update visible, ws free
        *(u16x8*)&wsb[0][sr * WS + sq * 8] = pr0;
        if (s2) *(u16x8*)&wsb[0][(sr + 128) * WS + sq * 8] = pr1;
        pr0 = *(const u16x8*)&W1z[sr * KP + 32 + sq * 8];
        if (s2) pr1 = *(const u16x8*)&W1z[(sr + 128) * KP + 32 + sq * 8];
        __syncthreads();                       // B1: ws[0] ready

        f32x4 acc[2][7];
        #pragma unroll
        for (int mi = 0; mi < 2; mi++)
            #pragma unroll
            for (int nj = 0; nj < 7; nj++)
                acc[mi][nj] = (f32x4){0.f, 0.f, 0.f, 0.f};

        for (int k = 0; k < 7; k++) {
            if (k < 6) {
                unsigned short* wb = wsb[(k + 1) & 1];
                *(u16x8*)&wb[sr * WS + sq * 8] = pr0;
                if (s2) *(u16x8*)&wb[(sr + 128) * WS + sq * 8] = pr1;
                const unsigned short* src = (k + 2 < 7) ? (W1z + (k + 2) * 32) : W2z;
                pr0 = *(const u16x8*)&src[sr * KP + sq * 8];
                if (s2) pr1 = *(const u16x8*)&src[(sr + 128) * KP + sq * 8];
            }
            const unsigned short* wr = wsb[k & 1];
            bf16x8 af[2], bfr[7];
            #pragma unroll
            for (int mi = 0; mi < 2; mi++)
                af[mi] = *(const bf16x8*)&hs[(wm + mi * 16 + fm) * HS + k * 32 + fq * 8];
            #pragma unroll
            for (int nj = 0; nj < 7; nj++)
                bfr[nj] = *(const bf16x8*)&wr[(wn + nj * 16 + fm) * WS + fq * 8];
            // swapped operands: n -> (fq*4+r), m -> fm
            #pragma unroll
            for (int mi = 0; mi < 2; mi++)
                #pragma unroll
                for (int nj = 0; nj < 7; nj++)
                    acc[mi][nj] = __builtin_amdgcn_mfma_f32_16x16x32_bf16(
                        bfr[nj], af[mi], acc[mi][nj], 0, 0, 0);
            __syncthreads();
        }

        // bias + tanh, pack (lane holds cols n=wn+nj*16+fq*4+{0..3} of row fm)
        unsigned int hidp[2][7][2];
        #pragma unroll
        for (int nj = 0; nj < 7; nj++) {
            const f32x4 b1v = *(const f32x4*)&bs[wn + nj * 16 + fq * 4];
            #pragma unroll
            for (int mi = 0; mi < 2; mi++) {
                const float t0 = fast_tanh(acc[mi][nj][0] + b1v[0]);
                const float t1 = fast_tanh(acc[mi][nj][1] + b1v[1]);
                const float t2 = fast_tanh(acc[mi][nj][2] + b1v[2]);
                const float t3 = fast_tanh(acc[mi][nj][3] + b1v[3]);
                hidp[mi][nj][0] = cvt_pk_bf16(t0, t1);
                hidp[mi][nj][1] = cvt_pk_bf16(t2, t3);
            }
        }

        // ================= phase 2: h += DT * (hid @ W2 + b2) ===============
        {
            *(u16x8*)&wsb[0][sr * WS + sq * 8] = pr0;
            if (s2) *(u16x8*)&wsb[0][(sr + 128) * WS + sq * 8] = pr1;
            pr0 = *(const u16x8*)&W2z[sr * KP + 32 + sq * 8];
            if (s2) pr1 = *(const u16x8*)&W2z[(sr + 128) * KP + 32 + sq * 8];
            // hid chunk 0 -> hc[0] (b64 vector writes, 2-way banks)
            #pragma unroll
            for (int t2 = 0; t2 < 2; t2++) {
                const int c0 = t2 * 16;
                if (c0 >= wn && c0 < wn + 112) {
                    const int nj = (c0 - wn) >> 4;
                    #pragma unroll
                    for (int mi = 0; mi < 2; mi++) {
                        u32x2 p; p[0] = hidp[mi][nj][0]; p[1] = hidp[mi][nj][1];
                        *(u32x2*)&hcb[0][(wm + mi * 16 + fm) * WS + t2 * 16 + fq * 4] = p;
                    }
                }
            }
        }
        __syncthreads();                       // ws[0]/hc[0] ready

        f32x4 fac[2][7];
        #pragma unroll
        for (int mi = 0; mi < 2; mi++)
            #pragma unroll
            for (int nj = 0; nj < 7; nj++)
                fac[mi][nj] = (f32x4){0.f, 0.f, 0.f, 0.f};

        for (int k = 0; k < 7; k++) {
            if (k < 6) {
                unsigned short* wb = wsb[(k + 1) & 1];
                unsigned short* hb = hcb[(k + 1) & 1];
                *(u16x8*)&wb[sr * WS + sq * 8] = pr0;
                if (s2) *(u16x8*)&wb[(sr + 128) * WS + sq * 8] = pr1;
                if (k + 2 < 7) {
                    pr0 = *(const u16x8*)&W2z[sr * KP + (k + 2) * 32 + sq * 8];
                    if (s2) pr1 = *(const u16x8*)&W2z[(sr + 128) * KP + (k + 2) * 32 + sq * 8];
                } else if (it != 3) {
                    pr0 = *(const u16x8*)&W1z[sr * KP + sq * 8];
                    if (s2) pr1 = *(const u16x8*)&W1z[(sr + 128) * KP + sq * 8];
                }
                // hid chunk k+1 -> hc[(k+1)&1] (b64 vector writes)
                #pragma unroll
                for (int t2 = 0; t2 < 2; t2++) {
                    const int c0 = (k + 1) * 32 + t2 * 16;
                    if (c0 >= wn && c0 < wn + 112) {
                        const int nj = (c0 - wn) >> 4;
                        #pragma unroll
                        for (int mi = 0; mi < 2; mi++) {
                            u32x2 p; p[0] = hidp[mi][nj][0]; p[1] = hidp[mi][nj][1];
                            *(u32x2*)&hb[(wm + mi * 16 + fm) * WS + t2 * 16 + fq * 4] = p;
                        }
                    }
                }
            }
            const unsigned short* wr = wsb[k & 1];
            const unsigned short* hr = hcb[k & 1];
            bf16x8 af2[2], bf2[7];
            #pragma unroll
            for (int mi = 0; mi < 2; mi++)
                af2[mi] = *(const bf16x8*)&hr[(wm + mi * 16 + fm) * WS + fq * 8];
            #pragma unroll
            for (int nj = 0; nj < 7; nj++)
                bf2[nj] = *(const bf16x8*)&wr[(wn + nj * 16 + fm) * WS + fq * 8];
            // swapped operands: n -> (fq*4+r), m -> fm
            #pragma unroll
            for (int mi = 0; mi < 2; mi++)
                #pragma unroll
                for (int nj = 0; nj < 7; nj++)
                    fac[mi][nj] = __builtin_amdgcn_mfma_f32_16x16x32_bf16(
                        bf2[nj], af2[mi], fac[mi][nj], 0, 0, 0);
            __syncthreads();
        }

        // h update: lane owns row (wm+mi*16+fm), cols n..n+3 -> b64 RMW
        #pragma unroll
        for (int nj = 0; nj < 7; nj++) {
            const int n = wn + nj * 16 + fq * 4;
            const f32x4 b2v = *(const f32x4*)&bs[224 + n];
            #pragma unroll
            for (int mi = 0; mi < 2; mi++) {
                const int m = wm + mi * 16 + fm;
                const ushort4 hv = *(const ushort4*)&hs[m * HS + n];
                const float v0 = bf2f(hv.x) + DT * (fac[mi][nj][0] + b2v[0]);
                const float v1 = bf2f(hv.y) + DT * (fac[mi][nj][1] + b2v[1]);
                const float v2 = bf2f(hv.z) + DT * (fac[mi][nj][2] + b2v[2]);
                const float v3 = bf2f(hv.w) + DT * (fac[mi][nj][3] + b2v[3]);
                u32x2 p; p[0] = cvt_pk_bf16(v0, v1); p[1] = cvt_pk_bf16(v2, v3);
                *(u32x2*)&hs[m * HS + n] = p;
            }
        }
        // next iteration's B0 barrier makes updates visible
    }

    __syncthreads();
    // write back h tile
    #pragma unroll
    for (int i = 0; i < 7; i++) {
        const int f = i * 512 + tid;
        const int r = f / 28, c = (f % 28) * 8;
        *(u16x8*)&hrow[(size_t)r * KP + c] = *(const u16x8*)&hs[r * HS + c];
    }
}

// ---------------------------------------------------------------------------
// Flash attention v7: v5's chunk-64 structure + Q in REGISTERS (aq[8]; qs
// LDS freed) + K/V LDS DOUBLE-BUFFER with ONE barrier per chunk (r24's
// verified schedule: barrier -> ds_read/MFMA cur || issue next loads ->
// store idle buffer). v6's failure was chunk=32 (compute phase too short to
// hide load latency); chunk=64 keeps 64 MFMAs + softmax per barrier.
// Race-free per r24's argument: conflicting buffer accesses are separated
// by the per-chunk barrier; psw stays wave-private (no barrier, as in v5).
// LDS 159,744 B. No-max softmax (scores bounded), of = pure MFMA accum.
// ---------------------------------------------------------------------------
__global__ __launch_bounds__(512) void flash_attn(
    const unsigned short* __restrict__ Qb, const unsigned short* __restrict__ Kb,
    const unsigned short* __restrict__ VT, unsigned short* __restrict__ ctx)
{
    constexpr int KS = 264;   // ks stride (u16)
    constexpr int VS = 72;    // vs stride
    constexpr int PS = 72;    // ps stride
    constexpr int BUF = 64 * KS + 256 * VS;   // 35,328 u16 per K/V buffer
    extern __shared__ unsigned short lds[];
    unsigned short* ps = lds + 2 * BUF;       // [8][16][72]

    const int tid = threadIdx.x;
    const int b = blockIdx.y, q0 = blockIdx.x * 128;
    const int lane = tid & 63, w = tid >> 6;
    const int fm = lane & 15, fq = lane >> 4;
    unsigned short* psw = ps + w * 16 * PS;

    const unsigned short* Qp = Qb + (size_t)b * Sc * Hc;
    const unsigned short* Kp = Kb + (size_t)b * Sc * Hc;
    const unsigned short* Vp = VT + (size_t)b * Hc * Sc;

    // Q tile in registers: row (q0 + w*16 + fm), 8 k-slices (32 VGPR)
    bf16x8 aq[8];
    #pragma unroll
    for (int kc = 0; kc < 8; kc++)
        aq[kc] = *(const bf16x8*)&Qp[(size_t)(q0 + w * 16 + fm) * Hc + kc * 32 + fq * 8];

    // staging registers (same per-thread assignment as v5's staging loop)
    u16x8 kreg[4], vreg[4];
    auto LOADC = [&](int c) {
        const int s0 = c * 64;
        #pragma unroll
        for (int i = 0; i < 4; i++) {
            const int v = i * 512 + tid;
            kreg[i] = *(const u16x8*)&Kp[(size_t)(s0 + (v >> 5)) * Hc + (v & 31) * 8];
            vreg[i] = *(const u16x8*)&Vp[(size_t)(v >> 3) * Sc + s0 + (v & 7) * 8];
        }
    };
    auto STOREC = [&](int buf) {
        unsigned short* ksd = lds + buf * BUF;
        unsigned short* vsd = ksd + 64 * KS;
        #pragma unroll
        for (int i = 0; i < 4; i++) {
            const int v = i * 512 + tid;
            *(u16x8*)&ksd[(v >> 5) * KS + (v & 31) * 8] = kreg[i];
            *(u16x8*)&vsd[(v >> 3) * VS + (v & 7) * 8] = vreg[i];
        }
    };

    f32x4 of[16];
    #pragma unroll
    for (int nj = 0; nj < 16; nj++) of[nj] = (f32x4){0.f, 0.f, 0.f, 0.f};
    float lrun[4] = {0.f, 0.f, 0.f, 0.f};

    // prologue: chunk 0 -> buffer 0
    LOADC(0);
    STOREC(0);

    for (int c = 0; c < 16; c++) {
        __syncthreads();        // buf[c&1] writes visible; buf[(c+1)&1] reads done
        const unsigned short* ksr = lds + (c & 1) * BUF;
        const unsigned short* vsr = ksr + 64 * KS;

        // issue next-chunk global loads (latency hides under MFMAs + softmax)
        if (c + 1 < 16) LOADC(c + 1);

        f32x4 sc[4];
        #pragma unroll
        for (int nj = 0; nj < 4; nj++) sc[nj] = (f32x4){0.f, 0.f, 0.f, 0.f};
        #pragma unroll
        for (int kc = 0; kc < 8; kc++) {
            #pragma unroll
            for (int nj = 0; nj < 4; nj++) {
                const bf16x8 bk = *(const bf16x8*)&ksr[(nj * 16 + fm) * KS + kc * 32 + fq * 8];
                sc[nj] = __builtin_amdgcn_mfma_f32_16x16x32_bf16(aq[kc], bk, sc[nj], 0, 0, 0);
            }
        }

        float rsum[4] = {0.f, 0.f, 0.f, 0.f};
        #pragma unroll
        for (int nj = 0; nj < 4; nj++)
            #pragma unroll
            for (int r = 0; r < 4; r++) {
                const float p = __expf(sc[nj][r]);
                rsum[r] += p;
                psw[(fq * 4 + r) * PS + nj * 16 + fm] = f2bf(p);
            }
        #pragma unroll
        for (int r = 0; r < 4; r++) {
            float s = rsum[r];
            #pragma unroll
            for (int o = 8; o > 0; o >>= 1) s += __shfl_xor(s, o, 64);
            lrun[r] += s;
        }

        #pragma unroll
        for (int t = 0; t < 2; t++) {
            const bf16x8 ap = *(const bf16x8*)&psw[fm * PS + t * 32 + fq * 8];
            #pragma unroll
            for (int nj = 0; nj < 16; nj++) {
                const bf16x8 bv = *(const bf16x8*)&vsr[(nj * 16 + fm) * VS + t * 32 + fq * 8];
                of[nj] = __builtin_amdgcn_mfma_f32_16x16x32_bf16(ap, bv, of[nj], 0, 0, 0);
            }
        }

        // store next chunk into the idle buffer
        if (c + 1 < 16) STOREC((c + 1) & 1);
    }

    float inv[4];
    #pragma unroll
    for (int r = 0; r < 4; r++) inv[r] = __frcp_rn(lrun[r]);
    #pragma unroll
    for (int nj = 0; nj < 16; nj++)
        #pragma unroll
        for (int r = 0; r < 4; r++)
            ctx[((size_t)b * Sc + q0 + w * 16 + fq * 4 + r) * Hc + nj * 16 + fm] =
                f2bf(of[nj][r] * inv[r]);
}

// ---------------------------------------------------------------------------
extern "C" void kernel_launch(void* const* d_in, const int* in_sizes, int n_in,
                              void* d_out, int out_size, void* d_ws, size_t ws_size,
                              hipStream_t stream)
{
    const float* eco_data = (const float*)d_in[0];
    const float* tran     = (const float*)d_in[1];
    const float* time_x   = (const float*)d_in[3];
    const float* W_eco    = (const float*)d_in[6];
    const float* b_eco    = (const float*)d_in[7];
    const float* W_in     = (const float*)d_in[8];
    const float* W_t      = (const float*)d_in[9];
    const float* b_in     = (const float*)d_in[10];
    const float* W_f1     = (const float*)d_in[11];
    const float* b_f1     = (const float*)d_in[12];
    const float* W_f2     = (const float*)d_in[13];
    const float* b_f2     = (const float*)d_in[14];
    const float* W_out    = (const float*)d_in[15];
    const float* b_out    = (const float*)d_in[16];
    const float* W_lin    = (const float*)d_in[17];
    const float* b_lin    = (const float*)d_in[18];
    float* out = (float*)d_out;

    // Workspace (offsets unchanged; P region unused)
    float* eco_vec = (float*)d_ws;
    unsigned short* hpad = (unsigned short*)(eco_vec + 8192);
    unsigned short* Qb = hpad + (size_t)3 * Mtot * KP;
    unsigned short* Kb = Qb + (size_t)Mtot * Hc;
    unsigned short* VT = Kb + (size_t)Mtot * Hc;
    unsigned short* P  = VT + (size_t)Mtot * Hc;   // unused
    unsigned short* WinT  = P + (size_t)Mtot * Sc;
    unsigned short* Wf1T  = WinT  + (size_t)3 * 256 * 256;
    unsigned short* Wf2T  = Wf1T  + (size_t)3 * 256 * KP;
    unsigned short* WoutT = Wf2T  + (size_t)3 * 256 * KP;
    unsigned short* WlinT = WoutT + (size_t)3 * 256 * KP;
    unsigned short* ctxb = hpad;                   // alias (h dead after qkv)

    // euler (r20) LDS: hs 59392 + 2x ws 17920 + 2x hc 10240 + bias 1792
    constexpr int EULER_LDS = 57856 * 2 + 448 * 4;
    static_assert(EULER_LDS == 117504, "euler lds");
    hipFuncSetAttribute((const void*)euler_fused,
                        hipFuncAttributeMaxDynamicSharedMemorySize, EULER_LDS);
    // flash v7 LDS: 2x (ks 33,792 + vs 36,864) + ps 18,432 = 159,744 B
    constexpr int FLASH_LDS = (2 * (64 * 264 + 256 * 72) + 8 * 16 * 72) * 2;
    static_assert(FLASH_LDS == 159744, "flash lds");
    hipFuncSetAttribute((const void*)flash_attn,
                        hipFuncAttributeMaxDynamicSharedMemorySize, FLASH_LDS);

    eco_kernel<<<Bc, Hc, 0, stream>>>(eco_data, W_eco, b_eco, eco_vec);

    // all 5 weight transposes in one dispatch (13 z-slices)
    wtrans_all<<<dim3(16, 16, 13), dim3(16, 16), 0, stream>>>(
        W_in, W_f1, W_f2, W_out, W_lin, WinT, Wf1T, Wf2T, WoutT, WlinT);

    const dim3 blk(256);

    // encode: hpad_k = tanh(tran @ W_in[k] + time_x*W_t[k] + b_in[k]), bf16 out
    mfma_gemm<MODE_ENC, float><<<dim3(2, 256, 3), blk, 0, stream>>>(
        tran, WinT, b_in, hpad, Mtot, KP, Hc, 256,
        0, 65536, Lc, (size_t)Mtot * KP, time_x, W_t, nullptr, nullptr, nullptr, nullptr);

    // fused 4-step Euler solve (r20 config: 128-row, HS=232/WS=40)
    euler_fused<<<dim3(Mtot / 128, 3), 512, EULER_LDS, stream>>>(
        hpad, Wf1T, Wf2T, b_f1, b_f2);

    // qkv: Q*scale, K, V^T (V^T via LDS bounce) written bf16
    mfma_gemm<MODE_QKV, unsigned short><<<dim3(2, 256, 3), blk, 0, stream>>>(
        hpad, WoutT, b_out, Qb, Mtot, Hc, KP, KP,
        (size_t)Mtot * KP, 57344, Hc, 0, nullptr, nullptr, eco_vec, tran, Kb, VT);

    // fused attention v7 (q-tile 128, chunk 64, K/V dbuf, 256 blocks)
    flash_attn<<<dim3(8, 32), 512, FLASH_LDS, stream>>>(Qb, Kb, VT, ctxb);

    // out = ctx @ W_lin + b_lin
    mfma_gemm<MODE_OUT, unsigned short><<<dim3(1, 256, 1), blk, 0, stream>>>(
        ctxb, WlinT, b_lin, out, Mtot, Pc, Hc, 256,
        0, 0, 0, 0, nullptr, nullptr, nullptr, nullptr, nullptr, nullptr);
}

// Round 14
// 495.150 us; speedup vs baseline: 1.0083x; 1.0083x over previous
//
#include <hip/hip_runtime.h>

// Problem constants (fixed by the reference)
constexpr int Bc = 32, Sc = 1024, Hc = 256, Pc = 96, Lc = 200, Oc = 200, Ec = 64;
constexpr int Mtot = Bc * Sc;
constexpr float DT = 0.25f;     // 1/N_EULER
constexpr int KP = 224;         // padded L/O dim (7*32)

enum { MODE_ENC = 0, MODE_QKV = 3, MODE_OUT = 4, MODE_BF16OUT = 5 };

typedef short bf16x8 __attribute__((ext_vector_type(8)));
typedef float f32x4 __attribute__((ext_vector_type(4)));
typedef unsigned short u16x8 __attribute__((ext_vector_type(8)));
typedef unsigned int u32x2 __attribute__((ext_vector_type(2)));

__device__ inline unsigned short f2bf(float x) {
    union { float f; unsigned int u; } v; v.f = x;
    unsigned int r = v.u + 0x7FFFu + ((v.u >> 16) & 1u);   // RNE
    return (unsigned short)(r >> 16);
}
__device__ inline float bf2f(unsigned short x) {
    union { unsigned int u; float f; } v; v.u = ((unsigned int)x) << 16;
    return v.f;
}
// rcp-form tanh: 1 - 2/(e^{2x}+1). 6 ops, no clamp needed:
// x->+inf: e=inf, rcp=0, y=1; x->-inf: e=0, rcp(1)=1, y=-1.
__device__ inline float fast_tanh(float x) {
    float e = __expf(2.f * x);
    float r = __frcp_rn(e + 1.f);
    return fmaf(-2.f, r, 1.f);
}
// pack two f32 -> two bf16 (RNE) in one instruction; lo=bf16(a), hi=bf16(b)
__device__ inline unsigned int cvt_pk_bf16(float a, float b) {
    unsigned int r;
    asm("v_cvt_pk_bf16_f32 %0, %1, %2" : "=v"(r) : "v"(a), "v"(b));
    return r;
}

// ---------------------------------------------------------------------------
__global__ __launch_bounds__(256) void eco_kernel(
    const float* __restrict__ eco_data, const float* __restrict__ W_eco,
    const float* __restrict__ b_eco, float* __restrict__ eco_vec)
{
    const int b = blockIdx.x, h = threadIdx.x;
    float acc = b_eco[h];
    #pragma unroll
    for (int e = 0; e < Ec; e++)
        acc = fmaf(eco_data[b * Ec + e], W_eco[(size_t)e * Hc + h], acc);
    eco_vec[(size_t)b * Hc + h] = acc;
}

// ---------------------------------------------------------------------------
// All five weight transposes in ONE dispatch (13 z-slices):
//   z 0-2 : W_in  [256][200] -> WinT  + z*256*256   (Kpad 256, Npad 256)
//   z 3-5 : W_f1  [200][200] -> Wf1T  + i*224*256   (Kpad 224, Npad 256)
//   z 6-8 : W_f2  [200][200] -> Wf2T  + i*224*256
//   z 9-11: W_out [200][256] -> WoutT + i*224*256
//   z 12  : W_lin [256][ 96] -> WlinT               (Kpad 256, Npad 128)
// ---------------------------------------------------------------------------
__global__ void wtrans_all(
    const float* __restrict__ W_in, const float* __restrict__ W_f1,
    const float* __restrict__ W_f2, const float* __restrict__ W_out,
    const float* __restrict__ W_lin,
    unsigned short* __restrict__ WinT, unsigned short* __restrict__ Wf1T,
    unsigned short* __restrict__ Wf2T, unsigned short* __restrict__ WoutT,
    unsigned short* __restrict__ WlinT)
{
    const int z = blockIdx.z;
    const int n = blockIdx.x * 16 + threadIdx.x;
    const int k = blockIdx.y * 16 + threadIdx.y;

    const float* W; unsigned short* WT;
    int K, N, Kpad, Npad;
    if (z < 3)       { W = W_in  + (size_t)z * 256 * 200;       WT = WinT  + (size_t)z * 256 * 256;       K = 256; N = 200; Kpad = 256; Npad = 256; }
    else if (z < 6)  { W = W_f1  + (size_t)(z - 3) * 200 * 200; WT = Wf1T  + (size_t)(z - 3) * 224 * 256; K = 200; N = 200; Kpad = 224; Npad = 256; }
    else if (z < 9)  { W = W_f2  + (size_t)(z - 6) * 200 * 200; WT = Wf2T  + (size_t)(z - 6) * 224 * 256; K = 200; N = 200; Kpad = 224; Npad = 256; }
    else if (z < 12) { W = W_out + (size_t)(z - 9) * 200 * 256; WT = WoutT + (size_t)(z - 9) * 224 * 256; K = 200; N = 256; Kpad = 224; Npad = 256; }
    else             { W = W_lin;                               WT = WlinT;                               K = 256; N =  96; Kpad = 256; Npad = 128; }

    if (n >= Npad || k >= Kpad) return;
    float v = (n < N && k < K) ? W[(size_t)k * N + n] : 0.f;
    WT[(size_t)n * Kpad + k] = f2bf(v);
}

// ---------------------------------------------------------------------------
// bf16 MFMA GEMM, 128x128 tile, 4 waves of 64x64, 16x16x32 MFMA.
// r24 (green, -23 us): LDS DOUBLE-BUFFER — 2x As/Bs (40,960 B), ONE barrier
// per k-step, next-tile global loads issued before this tile's MFMAs, stores
// into the idle buffer after. Race-free by construction: every conflicting
// access pair on a buffer is separated by the per-iteration barrier.
// MODE_QKV z==2 writes V^T via an LDS bounce (r14: -27 us).
// ---------------------------------------------------------------------------
template <int MODE, typename TA>
__global__ __launch_bounds__(256) void mfma_gemm(
    const TA* __restrict__ A, const unsigned short* __restrict__ WT,
    const float* __restrict__ bias, void* __restrict__ Cv,
    int M, int N, int K, int Kpad,
    size_t aStrideZ, size_t wStrideZ, size_t bStrideZ, size_t cStrideZ,
    const float* __restrict__ timev, const float* __restrict__ wtv,
    const float* __restrict__ eco, const float* __restrict__ trandat,
    unsigned short* __restrict__ Ck, unsigned short* __restrict__ Cvt)
{
    constexpr int LDS_S = 40;
    constexpr int HALF = 128 * LDS_S;            // 5120 u16 per array
    __shared__ unsigned short SM[4 * HALF];      // As0|Bs0|As1|Bs1  40,960 B

    const int tid = threadIdx.x;
    const int z = blockIdx.z;
    const int m0 = blockIdx.y * 128;
    const int n0 = blockIdx.x * 128;

    A    += (size_t)z * aStrideZ;
    WT   += (size_t)z * wStrideZ;
    bias += (size_t)z * bStrideZ;
    float* Cf = (float*)Cv + (size_t)z * cStrideZ;
    unsigned short* Cu = (unsigned short*)Cv + (size_t)z * cStrideZ;
    const float* wtp = wtv ? (wtv + (size_t)z * Lc) : nullptr;

    const int lane = tid & 63, wave = tid >> 6;
    const int wm = (wave & 1) * 64, wn = (wave >> 1) * 64;
    const int fm = lane & 15, fq = lane >> 4;

    f32x4 acc[4][4];
    #pragma unroll
    for (int i = 0; i < 4; i++)
        #pragma unroll
        for (int j = 0; j < 4; j++)
            acc[i][j] = (f32x4){0.f, 0.f, 0.f, 0.f};

    // staging registers
    float4  paf[4];
    ushort4 pau[4];
    u16x8   pb[2];

    auto LOAD = [&](int k0) {
        #pragma unroll
        for (int i = 0; i < 4; i++) {
            const int f = i * 256 + tid;
            const int row = f >> 3, kq = f & 7;
            if constexpr (sizeof(TA) == 4)
                paf[i] = *(const float4*)((const float*)A + (size_t)(m0 + row) * K + k0 + kq * 4);
            else
                pau[i] = *(const ushort4*)((const unsigned short*)A + (size_t)(m0 + row) * K + k0 + kq * 4);
        }
        #pragma unroll
        for (int i = 0; i < 2; i++) {
            const int f = i * 256 + tid;
            const int row = f >> 2, q = f & 3;
            pb[i] = *(const u16x8*)(WT + (size_t)(n0 + row) * Kpad + k0 + q * 8);
        }
    };
    auto STORE = [&](int buf) {
        unsigned short* Asd = SM + buf * 2 * HALF;
        unsigned short* Bsd = Asd + HALF;
        #pragma unroll
        for (int i = 0; i < 4; i++) {
            const int f = i * 256 + tid;
            const int row = f >> 3, kq = f & 7;
            ushort4 s;
            if constexpr (sizeof(TA) == 4) {
                s.x = f2bf(paf[i].x); s.y = f2bf(paf[i].y);
                s.z = f2bf(paf[i].z); s.w = f2bf(paf[i].w);
            } else {
                s = pau[i];
            }
            *(ushort4*)&Asd[row * LDS_S + kq * 4] = s;
        }
        #pragma unroll
        for (int i = 0; i < 2; i++) {
            const int f = i * 256 + tid;
            const int row = f >> 2, q = f & 3;
            *(u16x8*)&Bsd[row * LDS_S + q * 8] = pb[i];
        }
    };

    const int nk = K >> 5;
    // prologue: tile 0 -> buf0
    LOAD(0);
    STORE(0);

    for (int ki = 0; ki < nk; ki++) {
        __syncthreads();        // buf[ki&1] writes visible; buf[(ki+1)&1] reads done
        const unsigned short* Asr = SM + (ki & 1) * 2 * HALF;
        const unsigned short* Bsr = Asr + HALF;

        // issue next-tile global loads (latency hides under ds_reads + MFMAs)
        if (ki + 1 < nk) LOAD((ki + 1) * 32);

        bf16x8 af[4], bfr[4];
        #pragma unroll
        for (int mi = 0; mi < 4; mi++)
            af[mi] = *(const bf16x8*)&Asr[(wm + mi * 16 + fm) * LDS_S + fq * 8];
        #pragma unroll
        for (int nj = 0; nj < 4; nj++)
            bfr[nj] = *(const bf16x8*)&Bsr[(wn + nj * 16 + fm) * LDS_S + fq * 8];
        #pragma unroll
        for (int mi = 0; mi < 4; mi++)
            #pragma unroll
            for (int nj = 0; nj < 4; nj++)
                acc[mi][nj] = __builtin_amdgcn_mfma_f32_16x16x32_bf16(
                    af[mi], bfr[nj], acc[mi][nj], 0, 0, 0);

        // store next tile into the idle buffer
        if (ki + 1 < nk) STORE((ki + 1) & 1);
    }

    // ---- V^T epilogue (MODE_QKV, z==2): LDS bounce, coalesced writes ----
    if (MODE == MODE_QKV && z == 2) {
        constexpr int BSTR = 136;   // bounce row stride (u16); 64x136 fits in SM
        const int bq = m0 >> 10, sq0 = m0 & (Sc - 1);
        const int myhalf = wn >> 6;             // wave's n-half (0 or 1)
        #pragma unroll
        for (int half = 0; half < 2; half++) {
            __syncthreads();                    // SM free
            if (myhalf == half) {
                #pragma unroll
                for (int mi = 0; mi < 4; mi++)
                    #pragma unroll
                    for (int nj = 0; nj < 4; nj++) {
                        const int nn = n0 + wn + nj * 16 + fm;
                        const float bv = bias[nn];
                        const float ev = eco[(size_t)bq * Hc + nn];
                        #pragma unroll
                        for (int r = 0; r < 4; r++) {
                            const int mm = m0 + wm + mi * 16 + fq * 4 + r;
                            float v = acc[mi][nj][r] + bv + ev;
                            if (trandat[(size_t)mm * Hc + (Hc - 1)] == 0.f) v = 0.f;
                            SM[(nj * 16 + fm) * BSTR + wm + mi * 16 + fq * 4 + r] = f2bf(v);
                        }
                    }
            }
            __syncthreads();                    // bounce half ready
            #pragma unroll
            for (int i = 0; i < 4; i++) {
                const int vv = i * 256 + tid;   // 1024 = 64 rows x 16 vecs
                const int nl = vv >> 4, vc = vv & 15;
                *(u16x8*)&Cvt[((size_t)bq * Hc + n0 + half * 64 + nl) * Sc + sq0 + vc * 8] =
                    *(const u16x8*)&SM[nl * BSTR + vc * 8];
            }
        }
        return;
    }

    // ---- standard epilogue: C/D layout col = lane&15, row = quad*4 + reg ----
    #pragma unroll
    for (int mi = 0; mi < 4; mi++) {
        #pragma unroll
        for (int nj = 0; nj < 4; nj++) {
            const int nn = n0 + wn + nj * 16 + fm;
            if (nn >= N) continue;
            const float bv = (MODE == MODE_BF16OUT) ? 0.f
                           : ((MODE == MODE_ENC && nn >= Lc) ? 0.f : bias[nn]);
            #pragma unroll
            for (int r = 0; r < 4; r++) {
                const int mm = m0 + wm + mi * 16 + fq * 4 + r;
                float v = acc[mi][nj][r] + bv;
                if (MODE == MODE_ENC) {
                    float vv = (nn < Lc) ? fast_tanh(v + timev[mm] * wtp[nn]) : 0.f;
                    Cu[(size_t)mm * N + nn] = f2bf(vv);
                } else if (MODE == MODE_QKV) {
                    v += eco[(size_t)(mm >> 10) * Hc + nn];
                    if (trandat[(size_t)mm * Hc + (Hc - 1)] == 0.f) v = 0.f;
                    if (z == 0)      ((unsigned short*)Cv)[(size_t)mm * Hc + nn] = f2bf(v * 0.0625f);
                    else             Ck[(size_t)mm * Hc + nn] = f2bf(v);
                } else if (MODE == MODE_BF16OUT) {
                    Cu[(size_t)mm * N + nn] = f2bf(v);
                } else {
                    Cf[(size_t)mm * N + nn] = v;
                }
            }
        }
    }
}

// ---------------------------------------------------------------------------
// Fused 4-iteration Euler solve — r20 state VERBATIM (173.7-175.5 us green
// x3; 194 us on r13's slow container — serves as internal clock reference):
// r5/r16 structure + swapped-operand MFMA + b64 vector scatter/RMW + cvt_pk
// + bias LDS, HS=232/WS=40. CLOSED: 64-row (r11), destripe (r8).
// Dynamic LDS 117,504 B.
// ---------------------------------------------------------------------------
__global__ __launch_bounds__(512, 2) void euler_fused(
    unsigned short* __restrict__ hg,       // [3][M][224] bf16, in/out
    const unsigned short* __restrict__ W1, // [3][256][224] bf16
    const unsigned short* __restrict__ W2, // [3][256][224] bf16
    const float* __restrict__ b1g, const float* __restrict__ b2g)
{
    constexpr int HS = 232;   // h LDS stride (u16)
    constexpr int WS = 40;    // W / hid chunk stride (u16)
    extern __shared__ unsigned short lds[];
    unsigned short* hs  = lds;                 // [128][232]  59,392 B
    unsigned short* wsb[2] = { lds + 29696, lds + 38656 };   // [224][40] each
    unsigned short* hcb[2] = { lds + 47616, lds + 52736 };   // [128][40] each
    float* bs = (float*)(lds + 57856);         // b1[224] | b2[224]  1,792 B

    const int tid = threadIdx.x;
    const int z = blockIdx.y;
    const int m0 = blockIdx.x * 128;
    unsigned short* hrow = hg + ((size_t)z * Mtot + m0) * KP;
    const unsigned short* W1z = W1 + (size_t)z * 256 * KP;
    const unsigned short* W2z = W2 + (size_t)z * 256 * KP;

    const int lane = tid & 63, w = tid >> 6;
    const int wm = (w & 3) * 32, wn = (w >> 2) * 112;
    const int fm = lane & 15, fq = lane >> 4;

    const int sr = tid >> 2, sq = tid & 3;
    const bool s2 = (tid < 384);

    // stage biases into LDS (zero-padded to 224 each)
    if (tid < 448) {
        float v;
        if (tid < 224) v = (tid < Oc) ? b1g[z * Oc + tid] : 0.f;
        else { const int t = tid - 224; v = (t < Lc) ? b2g[z * Lc + t] : 0.f; }
        bs[tid] = v;
    }

    // prefetch W1 chunk 0
    u16x8 pr0, pr1;
    pr0 = *(const u16x8*)&W1z[sr * KP + sq * 8];
    if (s2) pr1 = *(const u16x8*)&W1z[(sr + 128) * KP + sq * 8];

    // stage h tile: 128 x 224
    #pragma unroll
    for (int i = 0; i < 7; i++) {
        const int f = i * 512 + tid;
        const int r = f / 28, c = (f % 28) * 8;
        *(u16x8*)&hs[r * HS + c] = *(const u16x8*)&hrow[(size_t)r * KP + c];
    }

    for (int it = 0; it < 4; it++) {
        // ================= phase 1: hid = tanh(h @ W1 + b1) =================
        __syncthreads();                       // B0: hs/update visible, ws free
        *(u16x8*)&wsb[0][sr * WS + sq * 8] = pr0;
        if (s2) *(u16x8*)&wsb[0][(sr + 128) * WS + sq * 8] = pr1;
        pr0 = *(const u16x8*)&W1z[sr * KP + 32 + sq * 8];
        if (s2) pr1 = *(const u16x8*)&W1z[(sr + 128) * KP + 32 + sq * 8];
        __syncthreads();                       // B1: ws[0] ready

        f32x4 acc[2][7];
        #pragma unroll
        for (int mi = 0; mi < 2; mi++)
            #pragma unroll
            for (int nj = 0; nj < 7; nj++)
                acc[mi][nj] = (f32x4){0.f, 0.f, 0.f, 0.f};

        for (int k = 0; k < 7; k++) {
            if (k < 6) {
                unsigned short* wb = wsb[(k + 1) & 1];
                *(u16x8*)&wb[sr * WS + sq * 8] = pr0;
                if (s2) *(u16x8*)&wb[(sr + 128) * WS + sq * 8] = pr1;
                const unsigned short* src = (k + 2 < 7) ? (W1z + (k + 2) * 32) : W2z;
                pr0 = *(const u16x8*)&src[sr * KP + sq * 8];
                if (s2) pr1 = *(const u16x8*)&src[(sr + 128) * KP + sq * 8];
            }
            const unsigned short* wr = wsb[k & 1];
            bf16x8 af[2], bfr[7];
            #pragma unroll
            for (int mi = 0; mi < 2; mi++)
                af[mi] = *(const bf16x8*)&hs[(wm + mi * 16 + fm) * HS + k * 32 + fq * 8];
            #pragma unroll
            for (int nj = 0; nj < 7; nj++)
                bfr[nj] = *(const bf16x8*)&wr[(wn + nj * 16 + fm) * WS + fq * 8];
            // swapped operands: n -> (fq*4+r), m -> fm
            #pragma unroll
            for (int mi = 0; mi < 2; mi++)
                #pragma unroll
                for (int nj = 0; nj < 7; nj++)
                    acc[mi][nj] = __builtin_amdgcn_mfma_f32_16x16x32_bf16(
                        bfr[nj], af[mi], acc[mi][nj], 0, 0, 0);
            __syncthreads();
        }

        // bias + tanh, pack (lane holds cols n=wn+nj*16+fq*4+{0..3} of row fm)
        unsigned int hidp[2][7][2];
        #pragma unroll
        for (int nj = 0; nj < 7; nj++) {
            const f32x4 b1v = *(const f32x4*)&bs[wn + nj * 16 + fq * 4];
            #pragma unroll
            for (int mi = 0; mi < 2; mi++) {
                const float t0 = fast_tanh(acc[mi][nj][0] + b1v[0]);
                const float t1 = fast_tanh(acc[mi][nj][1] + b1v[1]);
                const float t2 = fast_tanh(acc[mi][nj][2] + b1v[2]);
                const float t3 = fast_tanh(acc[mi][nj][3] + b1v[3]);
                hidp[mi][nj][0] = cvt_pk_bf16(t0, t1);
                hidp[mi][nj][1] = cvt_pk_bf16(t2, t3);
            }
        }

        // ================= phase 2: h += DT * (hid @ W2 + b2) ===============
        {
            *(u16x8*)&wsb[0][sr * WS + sq * 8] = pr0;
            if (s2) *(u16x8*)&wsb[0][(sr + 128) * WS + sq * 8] = pr1;
            pr0 = *(const u16x8*)&W2z[sr * KP + 32 + sq * 8];
            if (s2) pr1 = *(const u16x8*)&W2z[(sr + 128) * KP + 32 + sq * 8];
            // hid chunk 0 -> hc[0] (b64 vector writes, 2-way banks)
            #pragma unroll
            for (int t2 = 0; t2 < 2; t2++) {
                const int c0 = t2 * 16;
                if (c0 >= wn && c0 < wn + 112) {
                    const int nj = (c0 - wn) >> 4;
                    #pragma unroll
                    for (int mi = 0; mi < 2; mi++) {
                        u32x2 p; p[0] = hidp[mi][nj][0]; p[1] = hidp[mi][nj][1];
                        *(u32x2*)&hcb[0][(wm + mi * 16 + fm) * WS + t2 * 16 + fq * 4] = p;
                    }
                }
            }
        }
        __syncthreads();                       // ws[0]/hc[0] ready

        f32x4 fac[2][7];
        #pragma unroll
        for (int mi = 0; mi < 2; mi++)
            #pragma unroll
            for (int nj = 0; nj < 7; nj++)
                fac[mi][nj] = (f32x4){0.f, 0.f, 0.f, 0.f};

        for (int k = 0; k < 7; k++) {
            if (k < 6) {
                unsigned short* wb = wsb[(k + 1) & 1];
                unsigned short* hb = hcb[(k + 1) & 1];
                *(u16x8*)&wb[sr * WS + sq * 8] = pr0;
                if (s2) *(u16x8*)&wb[(sr + 128) * WS + sq * 8] = pr1;
                if (k + 2 < 7) {
                    pr0 = *(const u16x8*)&W2z[sr * KP + (k + 2) * 32 + sq * 8];
                    if (s2) pr1 = *(const u16x8*)&W2z[(sr + 128) * KP + (k + 2) * 32 + sq * 8];
                } else if (it != 3) {
                    pr0 = *(const u16x8*)&W1z[sr * KP + sq * 8];
                    if (s2) pr1 = *(const u16x8*)&W1z[(sr + 128) * KP + sq * 8];
                }
                // hid chunk k+1 -> hc[(k+1)&1] (b64 vector writes)
                #pragma unroll
                for (int t2 = 0; t2 < 2; t2++) {
                    const int c0 = (k + 1) * 32 + t2 * 16;
                    if (c0 >= wn && c0 < wn + 112) {
                        const int nj = (c0 - wn) >> 4;
                        #pragma unroll
                        for (int mi = 0; mi < 2; mi++) {
                            u32x2 p; p[0] = hidp[mi][nj][0]; p[1] = hidp[mi][nj][1];
                            *(u32x2*)&hb[(wm + mi * 16 + fm) * WS + t2 * 16 + fq * 4] = p;
                        }
                    }
                }
            }
            const unsigned short* wr = wsb[k & 1];
            const unsigned short* hr = hcb[k & 1];
            bf16x8 af2[2], bf2[7];
            #pragma unroll
            for (int mi = 0; mi < 2; mi++)
                af2[mi] = *(const bf16x8*)&hr[(wm + mi * 16 + fm) * WS + fq * 8];
            #pragma unroll
            for (int nj = 0; nj < 7; nj++)
                bf2[nj] = *(const bf16x8*)&wr[(wn + nj * 16 + fm) * WS + fq * 8];
            // swapped operands: n -> (fq*4+r), m -> fm
            #pragma unroll
            for (int mi = 0; mi < 2; mi++)
                #pragma unroll
                for (int nj = 0; nj < 7; nj++)
                    fac[mi][nj] = __builtin_amdgcn_mfma_f32_16x16x32_bf16(
                        bf2[nj], af2[mi], fac[mi][nj], 0, 0, 0);
            __syncthreads();
        }

        // h update: lane owns row (wm+mi*16+fm), cols n..n+3 -> b64 RMW
        #pragma unroll
        for (int nj = 0; nj < 7; nj++) {
            const int n = wn + nj * 16 + fq * 4;
            const f32x4 b2v = *(const f32x4*)&bs[224 + n];
            #pragma unroll
            for (int mi = 0; mi < 2; mi++) {
                const int m = wm + mi * 16 + fm;
                const ushort4 hv = *(const ushort4*)&hs[m * HS + n];
                const float v0 = bf2f(hv.x) + DT * (fac[mi][nj][0] + b2v[0]);
                const float v1 = bf2f(hv.y) + DT * (fac[mi][nj][1] + b2v[1]);
                const float v2 = bf2f(hv.z) + DT * (fac[mi][nj][2] + b2v[2]);
                const float v3 = bf2f(hv.w) + DT * (fac[mi][nj][3] + b2v[3]);
                u32x2 p; p[0] = cvt_pk_bf16(v0, v1); p[1] = cvt_pk_bf16(v2, v3);
                *(u32x2*)&hs[m * HS + n] = p;
            }
        }
        // next iteration's B0 barrier makes updates visible
    }

    __syncthreads();
    // write back h tile
    #pragma unroll
    for (int i = 0; i < 7; i++) {
        const int f = i * 512 + tid;
        const int r = f / 28, c = (f % 28) * 8;
        *(u16x8*)&hrow[(size_t)r * KP + c] = *(const u16x8*)&hs[r * HS + c];
    }
}

// ---------------------------------------------------------------------------
// Flash attention v7: v5's chunk-64 structure + Q in REGISTERS (aq[8]; qs
// LDS freed) + K/V LDS DOUBLE-BUFFER with ONE barrier per chunk (r24's
// verified schedule). r13 measured this AMBIGUOUSLY (container ran ~11%
// slow; euler-normalized total ~450 suggests v7 helped ~9 us). This round
// is the tie-break: identical resubmit, euler as internal clock reference.
// LDS 159,744 B.
// ---------------------------------------------------------------------------
__global__ __launch_bounds__(512) void flash_attn(
    const unsigned short* __restrict__ Qb, const unsigned short* __restrict__ Kb,
    const unsigned short* __restrict__ VT, unsigned short* __restrict__ ctx)
{
    constexpr int KS = 264;   // ks stride (u16)
    constexpr int VS = 72;    // vs stride
    constexpr int PS = 72;    // ps stride
    constexpr int BUF = 64 * KS + 256 * VS;   // 35,328 u16 per K/V buffer
    extern __shared__ unsigned short lds[];
    unsigned short* ps = lds + 2 * BUF;       // [8][16][72]

    const int tid = threadIdx.x;
    const int b = blockIdx.y, q0 = blockIdx.x * 128;
    const int lane = tid & 63, w = tid >> 6;
    const int fm = lane & 15, fq = lane >> 4;
    unsigned short* psw = ps + w * 16 * PS;

    const unsigned short* Qp = Qb + (size_t)b * Sc * Hc;
    const unsigned short* Kp = Kb + (size_t)b * Sc * Hc;
    const unsigned short* Vp = VT + (size_t)b * Hc * Sc;

    // Q tile in registers: row (q0 + w*16 + fm), 8 k-slices (32 VGPR)
    bf16x8 aq[8];
    #pragma unroll
    for (int kc = 0; kc < 8; kc++)
        aq[kc] = *(const bf16x8*)&Qp[(size_t)(q0 + w * 16 + fm) * Hc + kc * 32 + fq * 8];

    // staging registers (same per-thread assignment as v5's staging loop)
    u16x8 kreg[4], vreg[4];
    auto LOADC = [&](int c) {
        const int s0 = c * 64;
        #pragma unroll
        for (int i = 0; i < 4; i++) {
            const int v = i * 512 + tid;
            kreg[i] = *(const u16x8*)&Kp[(size_t)(s0 + (v >> 5)) * Hc + (v & 31) * 8];
            vreg[i] = *(const u16x8*)&Vp[(size_t)(v >> 3) * Sc + s0 + (v & 7) * 8];
        }
    };
    auto STOREC = [&](int buf) {
        unsigned short* ksd = lds + buf * BUF;
        unsigned short* vsd = ksd + 64 * KS;
        #pragma unroll
        for (int i = 0; i < 4; i++) {
            const int v = i * 512 + tid;
            *(u16x8*)&ksd[(v >> 5) * KS + (v & 31) * 8] = kreg[i];
            *(u16x8*)&vsd[(v >> 3) * VS + (v & 7) * 8] = vreg[i];
        }
    };

    f32x4 of[16];
    #pragma unroll
    for (int nj = 0; nj < 16; nj++) of[nj] = (f32x4){0.f, 0.f, 0.f, 0.f};
    float lrun[4] = {0.f, 0.f, 0.f, 0.f};

    // prologue: chunk 0 -> buffer 0
    LOADC(0);
    STOREC(0);

    for (int c = 0; c < 16; c++) {
        __syncthreads();        // buf[c&1] writes visible; buf[(c+1)&1] reads done
        const unsigned short* ksr = lds + (c & 1) * BUF;
        const unsigned short* vsr = ksr + 64 * KS;

        // issue next-chunk global loads (latency hides under MFMAs + softmax)
        if (c + 1 < 16) LOADC(c + 1);

        f32x4 sc[4];
        #pragma unroll
        for (int nj = 0; nj < 4; nj++) sc[nj] = (f32x4){0.f, 0.f, 0.f, 0.f};
        #pragma unroll
        for (int kc = 0; kc < 8; kc++) {
            #pragma unroll
            for (int nj = 0; nj < 4; nj++) {
                const bf16x8 bk = *(const bf16x8*)&ksr[(nj * 16 + fm) * KS + kc * 32 + fq * 8];
                sc[nj] = __builtin_amdgcn_mfma_f32_16x16x32_bf16(aq[kc], bk, sc[nj], 0, 0, 0);
            }
        }

        float rsum[4] = {0.f, 0.f, 0.f, 0.f};
        #pragma unroll
        for (int nj = 0; nj < 4; nj++)
            #pragma unroll
            for (int r = 0; r < 4; r++) {
                const float p = __expf(sc[nj][r]);
                rsum[r] += p;
                psw[(fq * 4 + r) * PS + nj * 16 + fm] = f2bf(p);
            }
        #pragma unroll
        for (int r = 0; r < 4; r++) {
            float s = rsum[r];
            #pragma unroll
            for (int o = 8; o > 0; o >>= 1) s += __shfl_xor(s, o, 64);
            lrun[r] += s;
        }

        #pragma unroll
        for (int t = 0; t < 2; t++) {
            const bf16x8 ap = *(const bf16x8*)&psw[fm * PS + t * 32 + fq * 8];
            #pragma unroll
            for (int nj = 0; nj < 16; nj++) {
                const bf16x8 bv = *(const bf16x8*)&vsr[(nj * 16 + fm) * VS + t * 32 + fq * 8];
                of[nj] = __builtin_amdgcn_mfma_f32_16x16x32_bf16(ap, bv, of[nj], 0, 0, 0);
            }
        }

        // store next chunk into the idle buffer
        if (c + 1 < 16) STOREC((c + 1) & 1);
    }

    float inv[4];
    #pragma unroll
    for (int r = 0; r < 4; r++) inv[r] = __frcp_rn(lrun[r]);
    #pragma unroll
    for (int nj = 0; nj < 16; nj++)
        #pragma unroll
        for (int r = 0; r < 4; r++)
            ctx[((size_t)b * Sc + q0 + w * 16 + fq * 4 + r) * Hc + nj * 16 + fm] =
                f2bf(of[nj][r] * inv[r]);
}

// ---------------------------------------------------------------------------
extern "C" void kernel_launch(void* const* d_in, const int* in_sizes, int n_in,
                              void* d_out, int out_size, void* d_ws, size_t ws_size,
                              hipStream_t stream)
{
    const float* eco_data = (const float*)d_in[0];
    const float* tran     = (const float*)d_in[1];
    const float* time_x   = (const float*)d_in[3];
    const float* W_eco    = (const float*)d_in[6];
    const float* b_eco    = (const float*)d_in[7];
    const float* W_in     = (const float*)d_in[8];
    const float* W_t      = (const float*)d_in[9];
    const float* b_in     = (const float*)d_in[10];
    const float* W_f1     = (const float*)d_in[11];
    const float* b_f1     = (const float*)d_in[12];
    const float* W_f2     = (const float*)d_in[13];
    const float* b_f2     = (const float*)d_in[14];
    const float* W_out    = (const float*)d_in[15];
    const float* b_out    = (const float*)d_in[16];
    const float* W_lin    = (const float*)d_in[17];
    const float* b_lin    = (const float*)d_in[18];
    float* out = (float*)d_out;

    // Workspace (offsets unchanged; P region unused)
    float* eco_vec = (float*)d_ws;
    unsigned short* hpad = (unsigned short*)(eco_vec + 8192);
    unsigned short* Qb = hpad + (size_t)3 * Mtot * KP;
    unsigned short* Kb = Qb + (size_t)Mtot * Hc;
    unsigned short* VT = Kb + (size_t)Mtot * Hc;
    unsigned short* P  = VT + (size_t)Mtot * Hc;   // unused
    unsigned short* WinT  = P + (size_t)Mtot * Sc;
    unsigned short* Wf1T  = WinT  + (size_t)3 * 256 * 256;
    unsigned short* Wf2T  = Wf1T  + (size_t)3 * 256 * KP;
    unsigned short* WoutT = Wf2T  + (size_t)3 * 256 * KP;
    unsigned short* WlinT = WoutT + (size_t)3 * 256 * KP;
    unsigned short* ctxb = hpad;                   // alias (h dead after qkv)

    // euler (r20) LDS: hs 59392 + 2x ws 17920 + 2x hc 10240 + bias 1792
    constexpr int EULER_LDS = 57856 * 2 + 448 * 4;
    static_assert(EULER_LDS == 117504, "euler lds");
    hipFuncSetAttribute((const void*)euler_fused,
                        hipFuncAttributeMaxDynamicSharedMemorySize, EULER_LDS);
    // flash v7 LDS: 2x (ks 33,792 + vs 36,864) + ps 18,432 = 159,744 B
    constexpr int FLASH_LDS = (2 * (64 * 264 + 256 * 72) + 8 * 16 * 72) * 2;
    static_assert(FLASH_LDS == 159744, "flash lds");
    hipFuncSetAttribute((const void*)flash_attn,
                        hipFuncAttributeMaxDynamicSharedMemorySize, FLASH_LDS);

    eco_kernel<<<Bc, Hc, 0, stream>>>(eco_data, W_eco, b_eco, eco_vec);

    // all 5 weight transposes in one dispatch (13 z-slices)
    wtrans_all<<<dim3(16, 16, 13), dim3(16, 16), 0, stream>>>(
        W_in, W_f1, W_f2, W_out, W_lin, WinT, Wf1T, Wf2T, WoutT, WlinT);

    const dim3 blk(256);

    // encode: hpad_k = tanh(tran @ W_in[k] + time_x*W_t[k] + b_in[k]), bf16 out
    mfma_gemm<MODE_ENC, float><<<dim3(2, 256, 3), blk, 0, stream>>>(
        tran, WinT, b_in, hpad, Mtot, KP, Hc, 256,
        0, 65536, Lc, (size_t)Mtot * KP, time_x, W_t, nullptr, nullptr, nullptr, nullptr);

    // fused 4-step Euler solve (r20 config: 128-row, HS=232/WS=40)
    euler_fused<<<dim3(Mtot / 128, 3), 512, EULER_LDS, stream>>>(
        hpad, Wf1T, Wf2T, b_f1, b_f2);

    // qkv: Q*scale, K, V^T (V^T via LDS bounce) written bf16
    mfma_gemm<MODE_QKV, unsigned short><<<dim3(2, 256, 3), blk, 0, stream>>>(
        hpad, WoutT, b_out, Qb, Mtot, Hc, KP, KP,
        (size_t)Mtot * KP, 57344, Hc, 0, nullptr, nullptr, eco_vec, tran, Kb, VT);

    // fused attention v7 (q-tile 128, chunk 64, K/V dbuf, 256 blocks)
    flash_attn<<<dim3(8, 32), 512, FLASH_LDS, stream>>>(Qb, Kb, VT, ctxb);

    // out = ctx @ W_lin + b_lin
    mfma_gemm<MODE_OUT, unsigned short><<<dim3(1, 256, 1), blk, 0, stream>>>(
        ctxb, WlinT, b_lin, out, Mtot, Pc, Hc, 256,
        0, 0, 0, 0, nullptr, nullptr, nullptr, nullptr, nullptr, nullptr);
}

// Round 16
// 442.521 us; speedup vs baseline: 1.1283x; 1.1189x over previous
//
#include <hip/hip_runtime.h>

// Problem constants (fixed by the reference)
constexpr int Bc = 32, Sc = 1024, Hc = 256, Pc = 96, Lc = 200, Oc = 200, Ec = 64;
constexpr int Mtot = Bc * Sc;
constexpr float DT = 0.25f;     // 1/N_EULER
constexpr int KP = 224;         // padded L/O dim (7*32)

enum { MODE_ENC = 0, MODE_QKV = 3, MODE_OUT = 4, MODE_BF16OUT = 5 };

typedef short bf16x8 __attribute__((ext_vector_type(8)));
typedef float f32x4 __attribute__((ext_vector_type(4)));
typedef unsigned short u16x8 __attribute__((ext_vector_type(8)));
typedef unsigned int u32x2 __attribute__((ext_vector_type(2)));

__device__ inline unsigned short f2bf(float x) {
    union { float f; unsigned int u; } v; v.f = x;
    unsigned int r = v.u + 0x7FFFu + ((v.u >> 16) & 1u);   // RNE
    return (unsigned short)(r >> 16);
}
__device__ inline float bf2f(unsigned short x) {
    union { unsigned int u; float f; } v; v.u = ((unsigned int)x) << 16;
    return v.f;
}
// rcp-form tanh: 1 - 2/(e^{2x}+1). 6 ops, no clamp needed:
// x->+inf: e=inf, rcp=0, y=1; x->-inf: e=0, rcp(1)=1, y=-1.
__device__ inline float fast_tanh(float x) {
    float e = __expf(2.f * x);
    float r = __frcp_rn(e + 1.f);
    return fmaf(-2.f, r, 1.f);
}
// pack two f32 -> two bf16 (RNE) in one instruction; lo=bf16(a), hi=bf16(b)
__device__ inline unsigned int cvt_pk_bf16(float a, float b) {
    unsigned int r;
    asm("v_cvt_pk_bf16_f32 %0, %1, %2" : "=v"(r) : "v"(a), "v"(b));
    return r;
}

// ---------------------------------------------------------------------------
__global__ __launch_bounds__(256) void eco_kernel(
    const float* __restrict__ eco_data, const float* __restrict__ W_eco,
    const float* __restrict__ b_eco, float* __restrict__ eco_vec)
{
    const int b = blockIdx.x, h = threadIdx.x;
    float acc = b_eco[h];
    #pragma unroll
    for (int e = 0; e < Ec; e++)
        acc = fmaf(eco_data[b * Ec + e], W_eco[(size_t)e * Hc + h], acc);
    eco_vec[(size_t)b * Hc + h] = acc;
}

// ---------------------------------------------------------------------------
// All five weight transposes in ONE dispatch (13 z-slices):
//   z 0-2 : W_in  [256][200] -> WinT  + z*256*256   (Kpad 256, Npad 256)
//   z 3-5 : W_f1  [200][200] -> Wf1T  + i*224*256   (Kpad 224, Npad 256)
//   z 6-8 : W_f2  [200][200] -> Wf2T  + i*224*256
//   z 9-11: W_out [200][256] -> WoutT + i*224*256
//   z 12  : W_lin [256][ 96] -> WlinT               (Kpad 256, Npad 128)
// ---------------------------------------------------------------------------
__global__ void wtrans_all(
    const float* __restrict__ W_in, const float* __restrict__ W_f1,
    const float* __restrict__ W_f2, const float* __restrict__ W_out,
    const float* __restrict__ W_lin,
    unsigned short* __restrict__ WinT, unsigned short* __restrict__ Wf1T,
    unsigned short* __restrict__ Wf2T, unsigned short* __restrict__ WoutT,
    unsigned short* __restrict__ WlinT)
{
    const int z = blockIdx.z;
    const int n = blockIdx.x * 16 + threadIdx.x;
    const int k = blockIdx.y * 16 + threadIdx.y;

    const float* W; unsigned short* WT;
    int K, N, Kpad, Npad;
    if (z < 3)       { W = W_in  + (size_t)z * 256 * 200;       WT = WinT  + (size_t)z * 256 * 256;       K = 256; N = 200; Kpad = 256; Npad = 256; }
    else if (z < 6)  { W = W_f1  + (size_t)(z - 3) * 200 * 200; WT = Wf1T  + (size_t)(z - 3) * 224 * 256; K = 200; N = 200; Kpad = 224; Npad = 256; }
    else if (z < 9)  { W = W_f2  + (size_t)(z - 6) * 200 * 200; WT = Wf2T  + (size_t)(z - 6) * 224 * 256; K = 200; N = 200; Kpad = 224; Npad = 256; }
    else if (z < 12) { W = W_out + (size_t)(z - 9) * 200 * 256; WT = WoutT + (size_t)(z - 9) * 224 * 256; K = 200; N = 256; Kpad = 224; Npad = 256; }
    else             { W = W_lin;                               WT = WlinT;                               K = 256; N =  96; Kpad = 256; Npad = 128; }

    if (n >= Npad || k >= Kpad) return;
    float v = (n < N && k < K) ? W[(size_t)k * N + n] : 0.f;
    WT[(size_t)n * Kpad + k] = f2bf(v);
}

// ---------------------------------------------------------------------------
// bf16 MFMA GEMM, 128x128 tile, 4 waves of 64x64, 16x16x32 MFMA.
// r24 (green, -23 us): LDS DOUBLE-BUFFER — 2x As/Bs (40,960 B), ONE barrier
// per k-step, next-tile global loads issued before this tile's MFMAs, stores
// into the idle buffer after. r26: ENC fp32->bf16 staging via cvt_pk
// (bit-identical RNE, 2 instrs vs 16+ scalar ops per float4).
// MODE_QKV z==2 writes V^T via an LDS bounce (r14: -27 us).
// ---------------------------------------------------------------------------
template <int MODE, typename TA>
__global__ __launch_bounds__(256) void mfma_gemm(
    const TA* __restrict__ A, const unsigned short* __restrict__ WT,
    const float* __restrict__ bias, void* __restrict__ Cv,
    int M, int N, int K, int Kpad,
    size_t aStrideZ, size_t wStrideZ, size_t bStrideZ, size_t cStrideZ,
    const float* __restrict__ timev, const float* __restrict__ wtv,
    const float* __restrict__ eco, const float* __restrict__ trandat,
    unsigned short* __restrict__ Ck, unsigned short* __restrict__ Cvt)
{
    constexpr int LDS_S = 40;
    constexpr int HALF = 128 * LDS_S;            // 5120 u16 per array
    __shared__ unsigned short SM[4 * HALF];      // As0|Bs0|As1|Bs1  40,960 B

    const int tid = threadIdx.x;
    const int z = blockIdx.z;
    const int m0 = blockIdx.y * 128;
    const int n0 = blockIdx.x * 128;

    A    += (size_t)z * aStrideZ;
    WT   += (size_t)z * wStrideZ;
    bias += (size_t)z * bStrideZ;
    float* Cf = (float*)Cv + (size_t)z * cStrideZ;
    unsigned short* Cu = (unsigned short*)Cv + (size_t)z * cStrideZ;
    const float* wtp = wtv ? (wtv + (size_t)z * Lc) : nullptr;

    const int lane = tid & 63, wave = tid >> 6;
    const int wm = (wave & 1) * 64, wn = (wave >> 1) * 64;
    const int fm = lane & 15, fq = lane >> 4;

    f32x4 acc[4][4];
    #pragma unroll
    for (int i = 0; i < 4; i++)
        #pragma unroll
        for (int j = 0; j < 4; j++)
            acc[i][j] = (f32x4){0.f, 0.f, 0.f, 0.f};

    // staging registers
    float4  paf[4];
    ushort4 pau[4];
    u16x8   pb[2];

    auto LOAD = [&](int k0) {
        #pragma unroll
        for (int i = 0; i < 4; i++) {
            const int f = i * 256 + tid;
            const int row = f >> 3, kq = f & 7;
            if constexpr (sizeof(TA) == 4)
                paf[i] = *(const float4*)((const float*)A + (size_t)(m0 + row) * K + k0 + kq * 4);
            else
                pau[i] = *(const ushort4*)((const unsigned short*)A + (size_t)(m0 + row) * K + k0 + kq * 4);
        }
        #pragma unroll
        for (int i = 0; i < 2; i++) {
            const int f = i * 256 + tid;
            const int row = f >> 2, q = f & 3;
            pb[i] = *(const u16x8*)(WT + (size_t)(n0 + row) * Kpad + k0 + q * 8);
        }
    };
    auto STORE = [&](int buf) {
        unsigned short* Asd = SM + buf * 2 * HALF;
        unsigned short* Bsd = Asd + HALF;
        #pragma unroll
        for (int i = 0; i < 4; i++) {
            const int f = i * 256 + tid;
            const int row = f >> 3, kq = f & 7;
            if constexpr (sizeof(TA) == 4) {
                u32x2 p;
                p[0] = cvt_pk_bf16(paf[i].x, paf[i].y);
                p[1] = cvt_pk_bf16(paf[i].z, paf[i].w);
                *(u32x2*)&Asd[row * LDS_S + kq * 4] = p;
            } else {
                *(ushort4*)&Asd[row * LDS_S + kq * 4] = pau[i];
            }
        }
        #pragma unroll
        for (int i = 0; i < 2; i++) {
            const int f = i * 256 + tid;
            const int row = f >> 2, q = f & 3;
            *(u16x8*)&Bsd[row * LDS_S + q * 8] = pb[i];
        }
    };

    const int nk = K >> 5;
    // prologue: tile 0 -> buf0
    LOAD(0);
    STORE(0);

    for (int ki = 0; ki < nk; ki++) {
        __syncthreads();        // buf[ki&1] writes visible; buf[(ki+1)&1] reads done
        const unsigned short* Asr = SM + (ki & 1) * 2 * HALF;
        const unsigned short* Bsr = Asr + HALF;

        // issue next-tile global loads (latency hides under ds_reads + MFMAs)
        if (ki + 1 < nk) LOAD((ki + 1) * 32);

        bf16x8 af[4], bfr[4];
        #pragma unroll
        for (int mi = 0; mi < 4; mi++)
            af[mi] = *(const bf16x8*)&Asr[(wm + mi * 16 + fm) * LDS_S + fq * 8];
        #pragma unroll
        for (int nj = 0; nj < 4; nj++)
            bfr[nj] = *(const bf16x8*)&Bsr[(wn + nj * 16 + fm) * LDS_S + fq * 8];
        #pragma unroll
        for (int mi = 0; mi < 4; mi++)
            #pragma unroll
            for (int nj = 0; nj < 4; nj++)
                acc[mi][nj] = __builtin_amdgcn_mfma_f32_16x16x32_bf16(
                    af[mi], bfr[nj], acc[mi][nj], 0, 0, 0);

        // store next tile into the idle buffer
        if (ki + 1 < nk) STORE((ki + 1) & 1);
    }

    // ---- V^T epilogue (MODE_QKV, z==2): LDS bounce, coalesced writes ----
    if (MODE == MODE_QKV && z == 2) {
        constexpr int BSTR = 136;   // bounce row stride (u16); 64x136 fits in SM
        const int bq = m0 >> 10, sq0 = m0 & (Sc - 1);
        const int myhalf = wn >> 6;             // wave's n-half (0 or 1)
        #pragma unroll
        for (int half = 0; half < 2; half++) {
            __syncthreads();                    // SM free
            if (myhalf == half) {
                #pragma unroll
                for (int mi = 0; mi < 4; mi++)
                    #pragma unroll
                    for (int nj = 0; nj < 4; nj++) {
                        const int nn = n0 + wn + nj * 16 + fm;
                        const float bv = bias[nn];
                        const float ev = eco[(size_t)bq * Hc + nn];
                        #pragma unroll
                        for (int r = 0; r < 4; r++) {
                            const int mm = m0 + wm + mi * 16 + fq * 4 + r;
                            float v = acc[mi][nj][r] + bv + ev;
                            if (trandat[(size_t)mm * Hc + (Hc - 1)] == 0.f) v = 0.f;
                            SM[(nj * 16 + fm) * BSTR + wm + mi * 16 + fq * 4 + r] = f2bf(v);
                        }
                    }
            }
            __syncthreads();                    // bounce half ready
            #pragma unroll
            for (int i = 0; i < 4; i++) {
                const int vv = i * 256 + tid;   // 1024 = 64 rows x 16 vecs
                const int nl = vv >> 4, vc = vv & 15;
                *(u16x8*)&Cvt[((size_t)bq * Hc + n0 + half * 64 + nl) * Sc + sq0 + vc * 8] =
                    *(const u16x8*)&SM[nl * BSTR + vc * 8];
            }
        }
        return;
    }

    // ---- standard epilogue: C/D layout col = lane&15, row = quad*4 + reg ----
    #pragma unroll
    for (int mi = 0; mi < 4; mi++) {
        #pragma unroll
        for (int nj = 0; nj < 4; nj++) {
            const int nn = n0 + wn + nj * 16 + fm;
            if (nn >= N) continue;
            const float bv = (MODE == MODE_BF16OUT) ? 0.f
                           : ((MODE == MODE_ENC && nn >= Lc) ? 0.f : bias[nn]);
            #pragma unroll
            for (int r = 0; r < 4; r++) {
                const int mm = m0 + wm + mi * 16 + fq * 4 + r;
                float v = acc[mi][nj][r] + bv;
                if (MODE == MODE_ENC) {
                    float vv = (nn < Lc) ? fast_tanh(v + timev[mm] * wtp[nn]) : 0.f;
                    Cu[(size_t)mm * N + nn] = f2bf(vv);
                } else if (MODE == MODE_QKV) {
                    v += eco[(size_t)(mm >> 10) * Hc + nn];
                    if (trandat[(size_t)mm * Hc + (Hc - 1)] == 0.f) v = 0.f;
                    if (z == 0)      ((unsigned short*)Cv)[(size_t)mm * Hc + nn] = f2bf(v * 0.0625f);
                    else             Ck[(size_t)mm * Hc + nn] = f2bf(v);
                } else if (MODE == MODE_BF16OUT) {
                    Cu[(size_t)mm * N + nn] = f2bf(v);
                } else {
                    Cf[(size_t)mm * N + nn] = v;
                }
            }
        }
    }
}

// ---------------------------------------------------------------------------
// Fused 4-iteration Euler solve — r20 state VERBATIM (175 us healthy /
// 194 us on the new slow-clock fleet — internal clock reference):
// r5/r16 structure + swapped-operand MFMA + b64 vector scatter/RMW + cvt_pk
// + bias LDS, HS=232/WS=40. CLOSED: 64-row (r11), destripe (r8).
// Dynamic LDS 117,504 B.
// ---------------------------------------------------------------------------
__global__ __launch_bounds__(512, 2) void euler_fused(
    unsigned short* __restrict__ hg,       // [3][M][224] bf16, in/out
    const unsigned short* __restrict__ W1, // [3][256][224] bf16
    const unsigned short* __restrict__ W2, // [3][256][224] bf16
    const float* __restrict__ b1g, const float* __restrict__ b2g)
{
    constexpr int HS = 232;   // h LDS stride (u16)
    constexpr int WS = 40;    // W / hid chunk stride (u16)
    extern __shared__ unsigned short lds[];
    unsigned short* hs  = lds;                 // [128][232]  59,392 B
    unsigned short* wsb[2] = { lds + 29696, lds + 38656 };   // [224][40] each
    unsigned short* hcb[2] = { lds + 47616, lds + 52736 };   // [128][40] each
    float* bs = (float*)(lds + 57856);         // b1[224] | b2[224]  1,792 B

    const int tid = threadIdx.x;
    const int z = blockIdx.y;
    const int m0 = blockIdx.x * 128;
    unsigned short* hrow = hg + ((size_t)z * Mtot + m0) * KP;
    const unsigned short* W1z = W1 + (size_t)z * 256 * KP;
    const unsigned short* W2z = W2 + (size_t)z * 256 * KP;

    const int lane = tid & 63, w = tid >> 6;
    const int wm = (w & 3) * 32, wn = (w >> 2) * 112;
    const int fm = lane & 15, fq = lane >> 4;

    const int sr = tid >> 2, sq = tid & 3;
    const bool s2 = (tid < 384);

    // stage biases into LDS (zero-padded to 224 each)
    if (tid < 448) {
        float v;
        if (tid < 224) v = (tid < Oc) ? b1g[z * Oc + tid] : 0.f;
        else { const int t = tid - 224; v = (t < Lc) ? b2g[z * Lc + t] : 0.f; }
        bs[tid] = v;
    }

    // prefetch W1 chunk 0
    u16x8 pr0, pr1;
    pr0 = *(const u16x8*)&W1z[sr * KP + sq * 8];
    if (s2) pr1 = *(const u16x8*)&W1z[(sr + 128) * KP + sq * 8];

    // stage h tile: 128 x 224
    #pragma unroll
    for (int i = 0; i < 7; i++) {
        const int f = i * 512 + tid;
        const int r = f / 28, c = (f % 28) * 8;
        *(u16x8*)&hs[r * HS + c] = *(const u16x8*)&hrow[(size_t)r * KP + c];
    }

    for (int it = 0; it < 4; it++) {
        // ================= phase 1: hid = tanh(h @ W1 + b1) =================
        __syncthreads();                       // B0: hs/update visible, ws free
        *(u16x8*)&wsb[0][sr * WS + sq * 8] = pr0;
        if (s2) *(u16x8*)&wsb[0][(sr + 128) * WS + sq * 8] = pr1;
        pr0 = *(const u16x8*)&W1z[sr * KP + 32 + sq * 8];
        if (s2) pr1 = *(const u16x8*)&W1z[(sr + 128) * KP + 32 + sq * 8];
        __syncthreads();                       // B1: ws[0] ready

        f32x4 acc[2][7];
        #pragma unroll
        for (int mi = 0; mi < 2; mi++)
            #pragma unroll
            for (int nj = 0; nj < 7; nj++)
                acc[mi][nj] = (f32x4){0.f, 0.f, 0.f, 0.f};

        for (int k = 0; k < 7; k++) {
            if (k < 6) {
                unsigned short* wb = wsb[(k + 1) & 1];
                *(u16x8*)&wb[sr * WS + sq * 8] = pr0;
                if (s2) *(u16x8*)&wb[(sr + 128) * WS + sq * 8] = pr1;
                const unsigned short* src = (k + 2 < 7) ? (W1z + (k + 2) * 32) : W2z;
                pr0 = *(const u16x8*)&src[sr * KP + sq * 8];
                if (s2) pr1 = *(const u16x8*)&src[(sr + 128) * KP + sq * 8];
            }
            const unsigned short* wr = wsb[k & 1];
            bf16x8 af[2], bfr[7];
            #pragma unroll
            for (int mi = 0; mi < 2; mi++)
                af[mi] = *(const bf16x8*)&hs[(wm + mi * 16 + fm) * HS + k * 32 + fq * 8];
            #pragma unroll
            for (int nj = 0; nj < 7; nj++)
                bfr[nj] = *(const bf16x8*)&wr[(wn + nj * 16 + fm) * WS + fq * 8];
            // swapped operands: n -> (fq*4+r), m -> fm
            #pragma unroll
            for (int mi = 0; mi < 2; mi++)
                #pragma unroll
                for (int nj = 0; nj < 7; nj++)
                    acc[mi][nj] = __builtin_amdgcn_mfma_f32_16x16x32_bf16(
                        bfr[nj], af[mi], acc[mi][nj], 0, 0, 0);
            __syncthreads();
        }

        // bias + tanh, pack (lane holds cols n=wn+nj*16+fq*4+{0..3} of row fm)
        unsigned int hidp[2][7][2];
        #pragma unroll
        for (int nj = 0; nj < 7; nj++) {
            const f32x4 b1v = *(const f32x4*)&bs[wn + nj * 16 + fq * 4];
            #pragma unroll
            for (int mi = 0; mi < 2; mi++) {
                const float t0 = fast_tanh(acc[mi][nj][0] + b1v[0]);
                const float t1 = fast_tanh(acc[mi][nj][1] + b1v[1]);
                const float t2 = fast_tanh(acc[mi][nj][2] + b1v[2]);
                const float t3 = fast_tanh(acc[mi][nj][3] + b1v[3]);
                hidp[mi][nj][0] = cvt_pk_bf16(t0, t1);
                hidp[mi][nj][1] = cvt_pk_bf16(t2, t3);
            }
        }

        // ================= phase 2: h += DT * (hid @ W2 + b2) ===============
        {
            *(u16x8*)&wsb[0][sr * WS + sq * 8] = pr0;
            if (s2) *(u16x8*)&wsb[0][(sr + 128) * WS + sq * 8] = pr1;
            pr0 = *(const u16x8*)&W2z[sr * KP + 32 + sq * 8];
            if (s2) pr1 = *(const u16x8*)&W2z[(sr + 128) * KP + 32 + sq * 8];
            // hid chunk 0 -> hc[0] (b64 vector writes, 2-way banks)
            #pragma unroll
            for (int t2 = 0; t2 < 2; t2++) {
                const int c0 = t2 * 16;
                if (c0 >= wn && c0 < wn + 112) {
                    const int nj = (c0 - wn) >> 4;
                    #pragma unroll
                    for (int mi = 0; mi < 2; mi++) {
                        u32x2 p; p[0] = hidp[mi][nj][0]; p[1] = hidp[mi][nj][1];
                        *(u32x2*)&hcb[0][(wm + mi * 16 + fm) * WS + t2 * 16 + fq * 4] = p;
                    }
                }
            }
        }
        __syncthreads();                       // ws[0]/hc[0] ready

        f32x4 fac[2][7];
        #pragma unroll
        for (int mi = 0; mi < 2; mi++)
            #pragma unroll
            for (int nj = 0; nj < 7; nj++)
                fac[mi][nj] = (f32x4){0.f, 0.f, 0.f, 0.f};

        for (int k = 0; k < 7; k++) {
            if (k < 6) {
                unsigned short* wb = wsb[(k + 1) & 1];
                unsigned short* hb = hcb[(k + 1) & 1];
                *(u16x8*)&wb[sr * WS + sq * 8] = pr0;
                if (s2) *(u16x8*)&wb[(sr + 128) * WS + sq * 8] = pr1;
                if (k + 2 < 7) {
                    pr0 = *(const u16x8*)&W2z[sr * KP + (k + 2) * 32 + sq * 8];
                    if (s2) pr1 = *(const u16x8*)&W2z[(sr + 128) * KP + (k + 2) * 32 + sq * 8];
                } else if (it != 3) {
                    pr0 = *(const u16x8*)&W1z[sr * KP + sq * 8];
                    if (s2) pr1 = *(const u16x8*)&W1z[(sr + 128) * KP + sq * 8];
                }
                // hid chunk k+1 -> hc[(k+1)&1] (b64 vector writes)
                #pragma unroll
                for (int t2 = 0; t2 < 2; t2++) {
                    const int c0 = (k + 1) * 32 + t2 * 16;
                    if (c0 >= wn && c0 < wn + 112) {
                        const int nj = (c0 - wn) >> 4;
                        #pragma unroll
                        for (int mi = 0; mi < 2; mi++) {
                            u32x2 p; p[0] = hidp[mi][nj][0]; p[1] = hidp[mi][nj][1];
                            *(u32x2*)&hb[(wm + mi * 16 + fm) * WS + t2 * 16 + fq * 4] = p;
                        }
                    }
                }
            }
            const unsigned short* wr = wsb[k & 1];
            const unsigned short* hr = hcb[k & 1];
            bf16x8 af2[2], bf2[7];
            #pragma unroll
            for (int mi = 0; mi < 2; mi++)
                af2[mi] = *(const bf16x8*)&hr[(wm + mi * 16 + fm) * WS + fq * 8];
            #pragma unroll
            for (int nj = 0; nj < 7; nj++)
                bf2[nj] = *(const bf16x8*)&wr[(wn + nj * 16 + fm) * WS + fq * 8];
            // swapped operands: n -> (fq*4+r), m -> fm
            #pragma unroll
            for (int mi = 0; mi < 2; mi++)
                #pragma unroll
                for (int nj = 0; nj < 7; nj++)
                    fac[mi][nj] = __builtin_amdgcn_mfma_f32_16x16x32_bf16(
                        bf2[nj], af2[mi], fac[mi][nj], 0, 0, 0);
            __syncthreads();
        }

        // h update: lane owns row (wm+mi*16+fm), cols n..n+3 -> b64 RMW
        #pragma unroll
        for (int nj = 0; nj < 7; nj++) {
            const int n = wn + nj * 16 + fq * 4;
            const f32x4 b2v = *(const f32x4*)&bs[224 + n];
            #pragma unroll
            for (int mi = 0; mi < 2; mi++) {
                const int m = wm + mi * 16 + fm;
                const ushort4 hv = *(const ushort4*)&hs[m * HS + n];
                const float v0 = bf2f(hv.x) + DT * (fac[mi][nj][0] + b2v[0]);
                const float v1 = bf2f(hv.y) + DT * (fac[mi][nj][1] + b2v[1]);
                const float v2 = bf2f(hv.z) + DT * (fac[mi][nj][2] + b2v[2]);
                const float v3 = bf2f(hv.w) + DT * (fac[mi][nj][3] + b2v[3]);
                u32x2 p; p[0] = cvt_pk_bf16(v0, v1); p[1] = cvt_pk_bf16(v2, v3);
                *(u32x2*)&hs[m * HS + n] = p;
            }
        }
        // next iteration's B0 barrier makes updates visible
    }

    __syncthreads();
    // write back h tile
    #pragma unroll
    for (int i = 0; i < 7; i++) {
        const int f = i * 512 + tid;
        const int r = f / 28, c = (f % 28) * 8;
        *(u16x8*)&hrow[(size_t)r * KP + c] = *(const u16x8*)&hs[r * HS + c];
    }
}

// ---------------------------------------------------------------------------
// Flash attention v8 = v7 (chunk-64, Q in regs, K/V dbuf, 1 barrier/chunk;
// confirmed -14 us vs v5 under consistent clock) + FUSED OUT GEMM epilogue:
// after the last chunk each wave holds its 16 ctx rows in of[16]; the K/V
// LDS is dead. Pack of/lrun -> bf16 into a wave-private bounce (the proven
// psw transpose pattern, no barrier needed), MFMA against WlinT fragments
// read from global (48 KB, L3-hot), write out fp32 directly. Eliminates the
// OUT kernel + ctx write/read round trip (2 x 16.8 MB). Safety: the 8
// wave-bounces span [0, 33792) u16 — entirely inside buf0 (35,328 u16);
// chunk 15 (c&1==1) reads only buf1, and each wave reads only its own
// bounce after its own writes (wave-private, in-order LDS). LDS 159,744 B.
// ---------------------------------------------------------------------------
__global__ __launch_bounds__(512) void flash_attn(
    const unsigned short* __restrict__ Qb, const unsigned short* __restrict__ Kb,
    const unsigned short* __restrict__ VT, const unsigned short* __restrict__ WlinT,
    const float* __restrict__ b_lin, float* __restrict__ outp)
{
    constexpr int KS = 264;   // ks stride (u16)
    constexpr int VS = 72;    // vs stride
    constexpr int PS = 72;    // ps stride
    constexpr int BUF = 64 * KS + 256 * VS;   // 35,328 u16 per K/V buffer
    constexpr int OS = 264;   // out-bounce row stride (u16)
    extern __shared__ unsigned short lds[];
    unsigned short* ps = lds + 2 * BUF;       // [8][16][72]

    const int tid = threadIdx.x;
    const int b = blockIdx.y, q0 = blockIdx.x * 128;
    const int lane = tid & 63, w = tid >> 6;
    const int fm = lane & 15, fq = lane >> 4;
    unsigned short* psw = ps + w * 16 * PS;

    const unsigned short* Qp = Qb + (size_t)b * Sc * Hc;
    const unsigned short* Kp = Kb + (size_t)b * Sc * Hc;
    const unsigned short* Vp = VT + (size_t)b * Hc * Sc;

    // Q tile in registers: row (q0 + w*16 + fm), 8 k-slices (32 VGPR)
    bf16x8 aq[8];
    #pragma unroll
    for (int kc = 0; kc < 8; kc++)
        aq[kc] = *(const bf16x8*)&Qp[(size_t)(q0 + w * 16 + fm) * Hc + kc * 32 + fq * 8];

    // staging registers (same per-thread assignment as v5's staging loop)
    u16x8 kreg[4], vreg[4];
    auto LOADC = [&](int c) {
        const int s0 = c * 64;
        #pragma unroll
        for (int i = 0; i < 4; i++) {
            const int v = i * 512 + tid;
            kreg[i] = *(const u16x8*)&Kp[(size_t)(s0 + (v >> 5)) * Hc + (v & 31) * 8];
            vreg[i] = *(const u16x8*)&Vp[(size_t)(v >> 3) * Sc + s0 + (v & 7) * 8];
        }
    };
    auto STOREC = [&](int buf) {
        unsigned short* ksd = lds + buf * BUF;
        unsigned short* vsd = ksd + 64 * KS;
        #pragma unroll
        for (int i = 0; i < 4; i++) {
            const int v = i * 512 + tid;
            *(u16x8*)&ksd[(v >> 5) * KS + (v & 31) * 8] = kreg[i];
            *(u16x8*)&vsd[(v >> 3) * VS + (v & 7) * 8] = vreg[i];
        }
    };

    f32x4 of[16];
    #pragma unroll
    for (int nj = 0; nj < 16; nj++) of[nj] = (f32x4){0.f, 0.f, 0.f, 0.f};
    float lrun[4] = {0.f, 0.f, 0.f, 0.f};

    // prologue: chunk 0 -> buffer 0
    LOADC(0);
    STOREC(0);

    for (int c = 0; c < 16; c++) {
        __syncthreads();        // buf[c&1] writes visible; buf[(c+1)&1] reads done
        const unsigned short* ksr = lds + (c & 1) * BUF;
        const unsigned short* vsr = ksr + 64 * KS;

        // issue next-chunk global loads (latency hides under MFMAs + softmax)
        if (c + 1 < 16) LOADC(c + 1);

        f32x4 sc[4];
        #pragma unroll
        for (int nj = 0; nj < 4; nj++) sc[nj] = (f32x4){0.f, 0.f, 0.f, 0.f};
        #pragma unroll
        for (int kc = 0; kc < 8; kc++) {
            #pragma unroll
            for (int nj = 0; nj < 4; nj++) {
                const bf16x8 bk = *(const bf16x8*)&ksr[(nj * 16 + fm) * KS + kc * 32 + fq * 8];
                sc[nj] = __builtin_amdgcn_mfma_f32_16x16x32_bf16(aq[kc], bk, sc[nj], 0, 0, 0);
            }
        }

        float rsum[4] = {0.f, 0.f, 0.f, 0.f};
        #pragma unroll
        for (int nj = 0; nj < 4; nj++)
            #pragma unroll
            for (int r = 0; r < 4; r++) {
                const float p = __expf(sc[nj][r]);
                rsum[r] += p;
                psw[(fq * 4 + r) * PS + nj * 16 + fm] = f2bf(p);
            }
        #pragma unroll
        for (int r = 0; r < 4; r++) {
            float s = rsum[r];
            #pragma unroll
            for (int o = 8; o > 0; o >>= 1) s += __shfl_xor(s, o, 64);
            lrun[r] += s;
        }

        #pragma unroll
        for (int t = 0; t < 2; t++) {
            const bf16x8 ap = *(const bf16x8*)&psw[fm * PS + t * 32 + fq * 8];
            #pragma unroll
            for (int nj = 0; nj < 16; nj++) {
                const bf16x8 bv = *(const bf16x8*)&vsr[(nj * 16 + fm) * VS + t * 32 + fq * 8];
                of[nj] = __builtin_amdgcn_mfma_f32_16x16x32_bf16(ap, bv, of[nj], 0, 0, 0);
            }
        }

        // store next chunk into the idle buffer
        if (c + 1 < 16) STOREC((c + 1) & 1);
    }

    // ---- fused OUT epilogue: out = (of/lrun) @ W_lin + b_lin ----
    float inv[4];
    #pragma unroll
    for (int r = 0; r < 4; r++) inv[r] = __frcp_rn(lrun[r]);

    // pack normalized ctx (bf16) into wave-private bounce inside buf0
    unsigned short* ws = lds + w * (16 * OS);
    #pragma unroll
    for (int nj = 0; nj < 16; nj++)
        #pragma unroll
        for (int r = 0; r < 4; r++)
            ws[(fq * 4 + r) * OS + nj * 16 + fm] = f2bf(of[nj][r] * inv[r]);

    f32x4 oacc[6];
    #pragma unroll
    for (int nj2 = 0; nj2 < 6; nj2++) oacc[nj2] = (f32x4){0.f, 0.f, 0.f, 0.f};
    #pragma unroll
    for (int kc = 0; kc < 8; kc++) {
        const bf16x8 ac = *(const bf16x8*)&ws[fm * OS + kc * 32 + fq * 8];
        #pragma unroll
        for (int nj2 = 0; nj2 < 6; nj2++) {
            const bf16x8 bw = *(const bf16x8*)&WlinT[(size_t)(nj2 * 16 + fm) * 256 + kc * 32 + fq * 8];
            oacc[nj2] = __builtin_amdgcn_mfma_f32_16x16x32_bf16(ac, bw, oacc[nj2], 0, 0, 0);
        }
    }
    #pragma unroll
    for (int nj2 = 0; nj2 < 6; nj2++) {
        const float bl = b_lin[nj2 * 16 + fm];
        #pragma unroll
        for (int r = 0; r < 4; r++)
            outp[(size_t)(b * Sc + q0 + w * 16 + fq * 4 + r) * Pc + nj2 * 16 + fm] =
                oacc[nj2][r] + bl;
    }
}

// ---------------------------------------------------------------------------
extern "C" void kernel_launch(void* const* d_in, const int* in_sizes, int n_in,
                              void* d_out, int out_size, void* d_ws, size_t ws_size,
                              hipStream_t stream)
{
    const float* eco_data = (const float*)d_in[0];
    const float* tran     = (const float*)d_in[1];
    const float* time_x   = (const float*)d_in[3];
    const float* W_eco    = (const float*)d_in[6];
    const float* b_eco    = (const float*)d_in[7];
    const float* W_in     = (const float*)d_in[8];
    const float* W_t      = (const float*)d_in[9];
    const float* b_in     = (const float*)d_in[10];
    const float* W_f1     = (const float*)d_in[11];
    const float* b_f1     = (const float*)d_in[12];
    const float* W_f2     = (const float*)d_in[13];
    const float* b_f2     = (const float*)d_in[14];
    const float* W_out    = (const float*)d_in[15];
    const float* b_out    = (const float*)d_in[16];
    const float* W_lin    = (const float*)d_in[17];
    const float* b_lin    = (const float*)d_in[18];
    float* out = (float*)d_out;

    // Workspace (offsets unchanged; P region unused)
    float* eco_vec = (float*)d_ws;
    unsigned short* hpad = (unsigned short*)(eco_vec + 8192);
    unsigned short* Qb = hpad + (size_t)3 * Mtot * KP;
    unsigned short* Kb = Qb + (size_t)Mtot * Hc;
    unsigned short* VT = Kb + (size_t)Mtot * Hc;
    unsigned short* P  = VT + (size_t)Mtot * Hc;   // unused
    unsigned short* WinT  = P + (size_t)Mtot * Sc;
    unsigned short* Wf1T  = WinT  + (size_t)3 * 256 * 256;
    unsigned short* Wf2T  = Wf1T  + (size_t)3 * 256 * KP;
    unsigned short* WoutT = Wf2T  + (size_t)3 * 256 * KP;
    unsigned short* WlinT = WoutT + (size_t)3 * 256 * KP;

    // euler (r20) LDS: hs 59392 + 2x ws 17920 + 2x hc 10240 + bias 1792
    constexpr int EULER_LDS = 57856 * 2 + 448 * 4;
    static_assert(EULER_LDS == 117504, "euler lds");
    hipFuncSetAttribute((const void*)euler_fused,
                        hipFuncAttributeMaxDynamicSharedMemorySize, EULER_LDS);
    // flash v8 LDS: 2x (ks 33,792 + vs 36,864) + ps 18,432 = 159,744 B
    constexpr int FLASH_LDS = (2 * (64 * 264 + 256 * 72) + 8 * 16 * 72) * 2;
    static_assert(FLASH_LDS == 159744, "flash lds");
    hipFuncSetAttribute((const void*)flash_attn,
                        hipFuncAttributeMaxDynamicSharedMemorySize, FLASH_LDS);

    eco_kernel<<<Bc, Hc, 0, stream>>>(eco_data, W_eco, b_eco, eco_vec);

    // all 5 weight transposes in one dispatch (13 z-slices)
    wtrans_all<<<dim3(16, 16, 13), dim3(16, 16), 0, stream>>>(
        W_in, W_f1, W_f2, W_out, W_lin, WinT, Wf1T, Wf2T, WoutT, WlinT);

    const dim3 blk(256);

    // encode: hpad_k = tanh(tran @ W_in[k] + time_x*W_t[k] + b_in[k]), bf16 out
    mfma_gemm<MODE_ENC, float><<<dim3(2, 256, 3), blk, 0, stream>>>(
        tran, WinT, b_in, hpad, Mtot, KP, Hc, 256,
        0, 65536, Lc, (size_t)Mtot * KP, time_x, W_t, nullptr, nullptr, nullptr, nullptr);

    // fused 4-step Euler solve (r20 config: 128-row, HS=232/WS=40)
    euler_fused<<<dim3(Mtot / 128, 3), 512, EULER_LDS, stream>>>(
        hpad, Wf1T, Wf2T, b_f1, b_f2);

    // qkv: Q*scale, K, V^T (V^T via LDS bounce) written bf16
    mfma_gemm<MODE_QKV, unsigned short><<<dim3(2, 256, 3), blk, 0, stream>>>(
        hpad, WoutT, b_out, Qb, Mtot, Hc, KP, KP,
        (size_t)Mtot * KP, 57344, Hc, 0, nullptr, nullptr, eco_vec, tran, Kb, VT);

    // fused attention v8 (q-tile 128, chunk 64, K/V dbuf, fused OUT epilogue)
    flash_attn<<<dim3(8, 32), 512, FLASH_LDS, stream>>>(
        Qb, Kb, VT, WlinT, b_lin, out);
}